// Round 1
// baseline (675.880 us; speedup 1.0000x reference)
//
#include <hip/hip_runtime.h>

#define NN 50000
#define NE 800000
#define CH 128
#define NG 64
#define OC 10

// ---------------- CSR build ----------------

__global__ __launch_bounds__(256) void k_zero(int* __restrict__ cnt) {
  int i = blockIdx.x * 256 + threadIdx.x;
  if (i < NN) cnt[i] = 0;
}

__global__ __launch_bounds__(256) void k_count(const int* __restrict__ dst, int* __restrict__ cnt) {
  int e = blockIdx.x * 256 + threadIdx.x;
  if (e < NE) atomicAdd(&cnt[dst[e]], 1);
}

__global__ __launch_bounds__(256) void k_dinv(const int* __restrict__ cnt, float* __restrict__ dinv) {
  int i = blockIdx.x * 256 + threadIdx.x;
  if (i < NN) dinv[i] = rsqrtf((float)(cnt[i] + 1));  // +1 = self loop; deg >= 1 always
}

__global__ __launch_bounds__(256) void k_scan1(const int* __restrict__ cnt, int* __restrict__ excl,
                                               int* __restrict__ bsum) {
  int t = threadIdx.x;
  int i = blockIdx.x * 256 + t;
  int v = (i < NN) ? cnt[i] : 0;
  __shared__ int s[256];
  s[t] = v;
  __syncthreads();
  for (int d = 1; d < 256; d <<= 1) {
    int x = (t >= d) ? s[t - d] : 0;
    __syncthreads();
    s[t] += x;
    __syncthreads();
  }
  if (i < NN) excl[i] = s[t] - v;
  if (t == 255) bsum[blockIdx.x] = s[255];
}

__global__ __launch_bounds__(256) void k_scan2(int* __restrict__ bsum, int nblocks) {
  int t = threadIdx.x;
  int v = (t < nblocks) ? bsum[t] : 0;
  __shared__ int s[256];
  s[t] = v;
  __syncthreads();
  for (int d = 1; d < 256; d <<= 1) {
    int x = (t >= d) ? s[t - d] : 0;
    __syncthreads();
    s[t] += x;
    __syncthreads();
  }
  if (t < nblocks) bsum[t] = s[t] - v;  // exclusive block offsets
}

__global__ __launch_bounds__(256) void k_scan3(int* __restrict__ rp, const int* __restrict__ bsum,
                                               int* __restrict__ cursor) {
  int i = blockIdx.x * 256 + threadIdx.x;
  if (i < NN) {
    int v = rp[i] + bsum[blockIdx.x];
    rp[i] = v;
    cursor[i] = v;
  }
}

__global__ __launch_bounds__(256) void k_fill(const int* __restrict__ src, const int* __restrict__ dst,
                                              int* __restrict__ cursor, const float* __restrict__ dinv,
                                              int* __restrict__ csrc, float* __restrict__ cw) {
  int e = blockIdx.x * 256 + threadIdx.x;
  if (e < NE) {
    int s = src[e], d = dst[e];
    int slot = atomicAdd(&cursor[d], 1);
    csrc[slot] = s;
    cw[slot] = dinv[s] * dinv[d];
  }
}

// ---------------- GEMM: T = f(A) @ W, A [NN][128], W [128][128] ----------------
// block = 256 thr (4 waves), 32 rows/block, lane covers 4 cols x 4 rows.
// LDS: W chunk 64x128 (32 KB) + A tile 32x128 (16 KB) = 48 KB -> 3 blocks/CU.

__device__ inline void fma4(float4& acc, float a, const float4& w) {
  acc.x = fmaf(a, w.x, acc.x);
  acc.y = fmaf(a, w.y, acc.y);
  acc.z = fmaf(a, w.z, acc.z);
  acc.w = fmaf(a, w.w, acc.w);
}

template <int RELU>
__global__ __launch_bounds__(256) void k_gemm(const float* __restrict__ A, const float* __restrict__ W,
                                              float* __restrict__ T) {
  __shared__ float4 sW[64 * 32];  // [k][c4]
  __shared__ float4 sA[32 * 32];  // [row][k4]
  const int t = threadIdx.x;
  const int brow = blockIdx.x * 32;

  // load A tile (coalesced float4), relu fused on read
#pragma unroll
  for (int i = 0; i < 4; ++i) {
    int f4 = t + i * 256;  // 0..1023
    int row = f4 >> 5, c4 = f4 & 31;
    float4 v = make_float4(0.f, 0.f, 0.f, 0.f);
    int gr = brow + row;
    if (gr < NN) v = ((const float4*)A)[gr * 32 + c4];
    if (RELU) {
      v.x = fmaxf(v.x, 0.f); v.y = fmaxf(v.y, 0.f);
      v.z = fmaxf(v.z, 0.f); v.w = fmaxf(v.w, 0.f);
    }
    sA[row * 32 + c4] = v;
  }

  float4 acc[4];
#pragma unroll
  for (int r = 0; r < 4; ++r) acc[r] = make_float4(0.f, 0.f, 0.f, 0.f);

  const int wv = t >> 6;            // wave 0..3 -> rows wv*8..wv*8+7
  const int rh = (t >> 5) & 1;      // half-wave row group
  const int cl = t & 31;            // col group: cols 4*cl..4*cl+3
  const int r0 = wv * 8 + rh * 4;

  for (int kc = 0; kc < 2; ++kc) {
    __syncthreads();  // protects sA stores (kc=0) and sW reuse (kc=1)
#pragma unroll
    for (int i = 0; i < 8; ++i) {
      int f4 = t + i * 256;  // 0..2047: k = f4>>5, c4 = f4&31
      sW[f4] = ((const float4*)W)[(kc * 64 + (f4 >> 5)) * 32 + (f4 & 31)];
    }
    __syncthreads();
#pragma unroll
    for (int k4 = 0; k4 < 16; ++k4) {
      float4 a4[4];
#pragma unroll
      for (int r = 0; r < 4; ++r) a4[r] = sA[(r0 + r) * 32 + kc * 16 + k4];
      float4 w0 = sW[(k4 * 4 + 0) * 32 + cl];
      float4 w1 = sW[(k4 * 4 + 1) * 32 + cl];
      float4 w2 = sW[(k4 * 4 + 2) * 32 + cl];
      float4 w3 = sW[(k4 * 4 + 3) * 32 + cl];
#pragma unroll
      for (int r = 0; r < 4; ++r) {
        fma4(acc[r], a4[r].x, w0);
        fma4(acc[r], a4[r].y, w1);
        fma4(acc[r], a4[r].z, w2);
        fma4(acc[r], a4[r].w, w3);
      }
    }
  }

#pragma unroll
  for (int r = 0; r < 4; ++r) {
    int gr = brow + r0 + r;
    if (gr < NN) ((float4*)T)[gr * 32 + cl] = acc[r];
  }
}

// ---------------- Aggregation: out[i] = b + dinv[i]^2 * T[i] + sum_e w_e * T[src_e] ----------------
// one wave per node; lane handles 2 channels (float2) -> 512 B coalesced gather per edge.

__global__ __launch_bounds__(256) void k_agg(const float* __restrict__ T, const int* __restrict__ rp,
                                             const int* __restrict__ cnt, const int* __restrict__ csrc,
                                             const float* __restrict__ cw, const float* __restrict__ dinv,
                                             const float* __restrict__ b, float* __restrict__ out) {
  int node = blockIdx.x * 4 + (threadIdx.x >> 6);
  int lane = threadIdx.x & 63;
  // grid is exact (12500*4 == 50000)
  float dv = dinv[node];
  float sn = dv * dv;
  float2 acc = *(const float2*)(b + 2 * lane);
  float2 tv = *(const float2*)(T + (size_t)node * CH + 2 * lane);
  acc.x = fmaf(sn, tv.x, acc.x);
  acc.y = fmaf(sn, tv.y, acc.y);
  int beg = rp[node];
  int num = cnt[node];
  for (int e = 0; e < num; ++e) {
    int s = csrc[beg + e];
    float w = cw[beg + e];
    float2 m = *(const float2*)(T + (size_t)s * CH + 2 * lane);
    acc.x = fmaf(w, m.x, acc.x);
    acc.y = fmaf(w, m.y, acc.y);
  }
  *(float2*)(out + (size_t)node * CH + 2 * lane) = acc;
}

// ---------------- Pool + final linear ----------------

__global__ __launch_bounds__(128) void k_pool(const float* __restrict__ nemb, const int* __restrict__ batch,
                                              const float* __restrict__ Wl, const float* __restrict__ bl,
                                              float* __restrict__ gout) {
  int g = blockIdx.x;
  int c = threadIdx.x;  // 0..127
  // lower_bound(batch, g) / lower_bound(batch, g+1) on sorted batch
  int lo = 0, hi = NN;
  while (lo < hi) { int mid = (lo + hi) >> 1; if (batch[mid] < g) lo = mid + 1; else hi = mid; }
  int beg = lo;
  lo = 0; hi = NN;
  while (lo < hi) { int mid = (lo + hi) >> 1; if (batch[mid] < g + 1) lo = mid + 1; else hi = mid; }
  int end = lo;

  float sum = 0.f;
  for (int n = beg; n < end; ++n) sum += nemb[(size_t)n * CH + c];
  float cntf = (float)(end - beg);
  float gv = sum / fmaxf(cntf, 1.0f);

  __shared__ float sg[CH];
  sg[c] = gv;
  __syncthreads();
  if (c < OC) {
    float o = bl[c];
    for (int k = 0; k < CH; ++k) o = fmaf(sg[k], Wl[k * OC + c], o);
    gout[g * OC + c] = o;
  }
}

// ---------------- launch ----------------

extern "C" void kernel_launch(void* const* d_in, const int* in_sizes, int n_in,
                              void* d_out, int out_size, void* d_ws, size_t ws_size,
                              hipStream_t stream) {
  const float* x = (const float*)d_in[0];
  const int* ei = (const int*)d_in[1];
  const int* src = ei;
  const int* dst = ei + NE;
  const int* batch = (const int*)d_in[2];
  const float* W1 = (const float*)d_in[3];
  const float* b1 = (const float*)d_in[4];
  const float* W2 = (const float*)d_in[5];
  const float* b2 = (const float*)d_in[6];
  const float* W3 = (const float*)d_in[7];
  const float* b3 = (const float*)d_in[8];
  const float* Wl = (const float*)d_in[9];
  const float* bl = (const float*)d_in[10];

  char* ws = (char*)d_ws;
  size_t off = 0;
  auto alloc = [&](size_t bytes) {
    void* p = ws + off;
    off += (bytes + 255) & ~(size_t)255;
    return p;
  };
  int* cnt = (int*)alloc(NN * 4);
  float* dinv = (float*)alloc(NN * 4);
  int* rp = (int*)alloc(NN * 4);
  int* cursor = (int*)alloc(NN * 4);
  int* bsum = (int*)alloc(256 * 4);
  int* csrc = (int*)alloc((size_t)NE * 4);
  float* cw = (float*)alloc((size_t)NE * 4);
  float* tbuf = (float*)alloc((size_t)NN * CH * 4);
  float* hbuf = (float*)alloc((size_t)NN * CH * 4);

  float* gout = (float*)d_out;
  float* nemb = (float*)d_out + NG * OC;

  const int nb_n = (NN + 255) / 256;  // 196
  const int nb_e = (NE + 255) / 256;  // 3125
  const int nb_g = (NN + 31) / 32;    // 1563
  const int nb_a = NN / 4;            // 12500

  k_zero<<<nb_n, 256, 0, stream>>>(cnt);
  k_count<<<nb_e, 256, 0, stream>>>(dst, cnt);
  k_dinv<<<nb_n, 256, 0, stream>>>(cnt, dinv);
  k_scan1<<<nb_n, 256, 0, stream>>>(cnt, rp, bsum);
  k_scan2<<<1, 256, 0, stream>>>(bsum, nb_n);
  k_scan3<<<nb_n, 256, 0, stream>>>(rp, bsum, cursor);
  k_fill<<<nb_e, 256, 0, stream>>>(src, dst, cursor, dinv, csrc, cw);

  // layer 1: t = x @ W1 ; h = agg(t) + b1   (relu deferred to next gemm read)
  k_gemm<0><<<nb_g, 256, 0, stream>>>(x, W1, tbuf);
  k_agg<<<nb_a, 256, 0, stream>>>(tbuf, rp, cnt, csrc, cw, dinv, b1, hbuf);
  // layer 2
  k_gemm<1><<<nb_g, 256, 0, stream>>>(hbuf, W2, tbuf);
  k_agg<<<nb_a, 256, 0, stream>>>(tbuf, rp, cnt, csrc, cw, dinv, b2, hbuf);
  // layer 3 -> n_emb straight into d_out
  k_gemm<1><<<nb_g, 256, 0, stream>>>(hbuf, W3, tbuf);
  k_agg<<<nb_a, 256, 0, stream>>>(tbuf, rp, cnt, csrc, cw, dinv, b3, nemb);
  // pool + final linear -> g_emb
  k_pool<<<NG, 128, 0, stream>>>(nemb, batch, Wl, bl, gout);
}

// Round 2
// 489.115 us; speedup vs baseline: 1.3818x; 1.3818x over previous
//
#include <hip/hip_runtime.h>

#define NN 50000
#define NE 800000
#define CH 128
#define NG 64
#define OC 10

// ---------------- CSR build ----------------

__global__ __launch_bounds__(256) void k_zero(int* __restrict__ cnt, float* __restrict__ gsum) {
  int i = blockIdx.x * 256 + threadIdx.x;
  if (i < NN) cnt[i] = 0;
  if (i < NG * CH) gsum[i] = 0.f;
}

__global__ __launch_bounds__(256) void k_count(const int* __restrict__ dst, int* __restrict__ cnt) {
  int e = blockIdx.x * 256 + threadIdx.x;
  if (e < NE) atomicAdd(&cnt[dst[e]], 1);
}

__global__ __launch_bounds__(256) void k_dinv(const int* __restrict__ cnt, float* __restrict__ dinv) {
  int i = blockIdx.x * 256 + threadIdx.x;
  if (i < NN) dinv[i] = rsqrtf((float)(cnt[i] + 1));  // +1 = self loop; deg >= 1 always
}

__global__ __launch_bounds__(256) void k_scan1(const int* __restrict__ cnt, int* __restrict__ excl,
                                               int* __restrict__ bsum) {
  int t = threadIdx.x;
  int i = blockIdx.x * 256 + t;
  int v = (i < NN) ? cnt[i] : 0;
  __shared__ int s[256];
  s[t] = v;
  __syncthreads();
  for (int d = 1; d < 256; d <<= 1) {
    int x = (t >= d) ? s[t - d] : 0;
    __syncthreads();
    s[t] += x;
    __syncthreads();
  }
  if (i < NN) excl[i] = s[t] - v;
  if (t == 255) bsum[blockIdx.x] = s[255];
}

__global__ __launch_bounds__(256) void k_scan2(int* __restrict__ bsum, int nblocks) {
  int t = threadIdx.x;
  int v = (t < nblocks) ? bsum[t] : 0;
  __shared__ int s[256];
  s[t] = v;
  __syncthreads();
  for (int d = 1; d < 256; d <<= 1) {
    int x = (t >= d) ? s[t - d] : 0;
    __syncthreads();
    s[t] += x;
    __syncthreads();
  }
  if (t < nblocks) bsum[t] = s[t] - v;  // exclusive block offsets
}

__global__ __launch_bounds__(256) void k_scan3(int* __restrict__ rp, const int* __restrict__ bsum,
                                               int* __restrict__ cursor) {
  int i = blockIdx.x * 256 + threadIdx.x;
  if (i < NN) {
    int v = rp[i] + bsum[blockIdx.x];
    rp[i] = v;
    cursor[i] = v;
  }
}

__global__ __launch_bounds__(256) void k_fill(const int* __restrict__ src, const int* __restrict__ dst,
                                              int* __restrict__ cursor, const float* __restrict__ dinv,
                                              int* __restrict__ csrc, float* __restrict__ cw) {
  int e = blockIdx.x * 256 + threadIdx.x;
  if (e < NE) {
    int s = src[e], d = dst[e];
    int slot = atomicAdd(&cursor[d], 1);
    csrc[slot] = s;
    cw[slot] = dinv[s] * dinv[d];
  }
}

// ---------------- GEMM: T = f(A) @ W, A [NN][128], W [128][128] ----------------
// block = 256 thr (4 waves), 32 rows/block, lane covers 4 cols x 4 rows.
// LDS: W chunk 64x128 (32 KB) + A tile 32x128 (16 KB) = 48 KB -> 3 blocks/CU.

__device__ inline void fma4(float4& acc, float a, const float4& w) {
  acc.x = fmaf(a, w.x, acc.x);
  acc.y = fmaf(a, w.y, acc.y);
  acc.z = fmaf(a, w.z, acc.z);
  acc.w = fmaf(a, w.w, acc.w);
}

template <int RELU>
__global__ __launch_bounds__(256) void k_gemm(const float* __restrict__ A, const float* __restrict__ W,
                                              float* __restrict__ T) {
  __shared__ float4 sW[64 * 32];  // [k][c4]
  __shared__ float4 sA[32 * 32];  // [row][k4]
  const int t = threadIdx.x;
  const int brow = blockIdx.x * 32;

  // load A tile (coalesced float4), relu fused on read
#pragma unroll
  for (int i = 0; i < 4; ++i) {
    int f4 = t + i * 256;  // 0..1023
    int row = f4 >> 5, c4 = f4 & 31;
    float4 v = make_float4(0.f, 0.f, 0.f, 0.f);
    int gr = brow + row;
    if (gr < NN) v = ((const float4*)A)[gr * 32 + c4];
    if (RELU) {
      v.x = fmaxf(v.x, 0.f); v.y = fmaxf(v.y, 0.f);
      v.z = fmaxf(v.z, 0.f); v.w = fmaxf(v.w, 0.f);
    }
    sA[row * 32 + c4] = v;
  }

  float4 acc[4];
#pragma unroll
  for (int r = 0; r < 4; ++r) acc[r] = make_float4(0.f, 0.f, 0.f, 0.f);

  const int wv = t >> 6;            // wave 0..3 -> rows wv*8..wv*8+7
  const int rh = (t >> 5) & 1;      // half-wave row group
  const int cl = t & 31;            // col group: cols 4*cl..4*cl+3
  const int r0 = wv * 8 + rh * 4;

  for (int kc = 0; kc < 2; ++kc) {
    __syncthreads();  // protects sA stores (kc=0) and sW reuse (kc=1)
#pragma unroll
    for (int i = 0; i < 8; ++i) {
      int f4 = t + i * 256;  // 0..2047: k = f4>>5, c4 = f4&31
      sW[f4] = ((const float4*)W)[(kc * 64 + (f4 >> 5)) * 32 + (f4 & 31)];
    }
    __syncthreads();
#pragma unroll
    for (int k4 = 0; k4 < 16; ++k4) {
      float4 a4[4];
#pragma unroll
      for (int r = 0; r < 4; ++r) a4[r] = sA[(r0 + r) * 32 + kc * 16 + k4];
      float4 w0 = sW[(k4 * 4 + 0) * 32 + cl];
      float4 w1 = sW[(k4 * 4 + 1) * 32 + cl];
      float4 w2 = sW[(k4 * 4 + 2) * 32 + cl];
      float4 w3 = sW[(k4 * 4 + 3) * 32 + cl];
#pragma unroll
      for (int r = 0; r < 4; ++r) {
        fma4(acc[r], a4[r].x, w0);
        fma4(acc[r], a4[r].y, w1);
        fma4(acc[r], a4[r].z, w2);
        fma4(acc[r], a4[r].w, w3);
      }
    }
  }

#pragma unroll
  for (int r = 0; r < 4; ++r) {
    int gr = brow + r0 + r;
    if (gr < NN) ((float4*)T)[gr * 32 + cl] = acc[r];
  }
}

// ---------------- Aggregation: out[i] = b + dinv[i]^2 * T[i] + sum_e w_e * T[src_e] ----------------
// one wave per node; lane handles 2 channels (float2) -> 512 B coalesced gather per edge.

__global__ __launch_bounds__(256) void k_agg(const float* __restrict__ T, const int* __restrict__ rp,
                                             const int* __restrict__ cnt, const int* __restrict__ csrc,
                                             const float* __restrict__ cw, const float* __restrict__ dinv,
                                             const float* __restrict__ b, float* __restrict__ out) {
  int node = blockIdx.x * 4 + (threadIdx.x >> 6);
  int lane = threadIdx.x & 63;
  // grid is exact (12500*4 == 50000)
  float dv = dinv[node];
  float sn = dv * dv;
  float2 acc = *(const float2*)(b + 2 * lane);
  float2 tv = *(const float2*)(T + (size_t)node * CH + 2 * lane);
  acc.x = fmaf(sn, tv.x, acc.x);
  acc.y = fmaf(sn, tv.y, acc.y);
  int beg = rp[node];
  int num = cnt[node];
  for (int e = 0; e < num; ++e) {
    int s = csrc[beg + e];
    float w = cw[beg + e];
    float2 m = *(const float2*)(T + (size_t)s * CH + 2 * lane);
    acc.x = fmaf(w, m.x, acc.x);
    acc.y = fmaf(w, m.y, acc.y);
  }
  *(float2*)(out + (size_t)node * CH + 2 * lane) = acc;
}

// ---------------- Pool (2-stage) + final linear ----------------
// stage 1: 64 graphs x 32 chunks; each block partial-sums its chunk and
// atomicAdds 128 floats into gsum. stage 2: divide by count + g @ Wl + bl.

#define PCHUNK 32

__global__ __launch_bounds__(128) void k_pool1(const float* __restrict__ nemb,
                                               const int* __restrict__ batch,
                                               float* __restrict__ gsum) {
  int g = blockIdx.x >> 5;       // graph 0..63
  int ck = blockIdx.x & (PCHUNK - 1);
  int c = threadIdx.x;           // channel 0..127
  // lower_bound(batch, g), lower_bound(batch, g+1) — uniform across block
  int lo = 0, hi = NN;
  while (lo < hi) { int m = (lo + hi) >> 1; if (batch[m] < g) lo = m + 1; else hi = m; }
  int beg = lo;
  hi = NN;
  while (lo < hi) { int m = (lo + hi) >> 1; if (batch[m] < g + 1) lo = m + 1; else hi = m; }
  int end = lo;
  int len = end - beg;
  int c0 = beg + (int)(((long long)len * ck) >> 5);
  int c1 = beg + (int)(((long long)len * (ck + 1)) >> 5);
  float sum = 0.f;
  for (int n = c0; n < c1; ++n) sum += nemb[(size_t)n * CH + c];
  atomicAdd(&gsum[g * CH + c], sum);
}

__global__ __launch_bounds__(128) void k_pool2(const float* __restrict__ gsum,
                                               const int* __restrict__ batch,
                                               const float* __restrict__ Wl,
                                               const float* __restrict__ bl,
                                               float* __restrict__ gout) {
  int g = blockIdx.x;
  int c = threadIdx.x;  // 0..127
  int lo = 0, hi = NN;
  while (lo < hi) { int m = (lo + hi) >> 1; if (batch[m] < g) lo = m + 1; else hi = m; }
  int beg = lo;
  hi = NN;
  while (lo < hi) { int m = (lo + hi) >> 1; if (batch[m] < g + 1) lo = m + 1; else hi = m; }
  int end = lo;
  float gv = gsum[g * CH + c] / fmaxf((float)(end - beg), 1.0f);

  __shared__ float sg[CH];
  sg[c] = gv;
  __syncthreads();
  if (c < OC) {
    float o = bl[c];
    for (int k = 0; k < CH; ++k) o = fmaf(sg[k], Wl[k * OC + c], o);
    gout[g * OC + c] = o;
  }
}

// ---------------- launch ----------------

extern "C" void kernel_launch(void* const* d_in, const int* in_sizes, int n_in,
                              void* d_out, int out_size, void* d_ws, size_t ws_size,
                              hipStream_t stream) {
  const float* x = (const float*)d_in[0];
  const int* ei = (const int*)d_in[1];
  const int* src = ei;
  const int* dst = ei + NE;
  const int* batch = (const int*)d_in[2];
  const float* W1 = (const float*)d_in[3];
  const float* b1 = (const float*)d_in[4];
  const float* W2 = (const float*)d_in[5];
  const float* b2 = (const float*)d_in[6];
  const float* W3 = (const float*)d_in[7];
  const float* b3 = (const float*)d_in[8];
  const float* Wl = (const float*)d_in[9];
  const float* bl = (const float*)d_in[10];

  char* ws = (char*)d_ws;
  size_t off = 0;
  auto alloc = [&](size_t bytes) {
    void* p = ws + off;
    off += (bytes + 255) & ~(size_t)255;
    return p;
  };
  int* cnt = (int*)alloc(NN * 4);
  float* dinv = (float*)alloc(NN * 4);
  int* rp = (int*)alloc(NN * 4);
  int* cursor = (int*)alloc(NN * 4);
  int* bsum = (int*)alloc(256 * 4);
  int* csrc = (int*)alloc((size_t)NE * 4);
  float* cw = (float*)alloc((size_t)NE * 4);
  float* tbuf = (float*)alloc((size_t)NN * CH * 4);
  float* hbuf = (float*)alloc((size_t)NN * CH * 4);
  float* gsum = (float*)alloc((size_t)NG * CH * 4);

  float* gout = (float*)d_out;
  float* nemb = (float*)d_out + NG * OC;

  const int nb_n = (NN + 255) / 256;  // 196
  const int nb_e = (NE + 255) / 256;  // 3125
  const int nb_g = (NN + 31) / 32;    // 1563
  const int nb_a = NN / 4;            // 12500

  k_zero<<<nb_n, 256, 0, stream>>>(cnt, gsum);
  k_count<<<nb_e, 256, 0, stream>>>(dst, cnt);
  k_dinv<<<nb_n, 256, 0, stream>>>(cnt, dinv);
  k_scan1<<<nb_n, 256, 0, stream>>>(cnt, rp, bsum);
  k_scan2<<<1, 256, 0, stream>>>(bsum, nb_n);
  k_scan3<<<nb_n, 256, 0, stream>>>(rp, bsum, cursor);
  k_fill<<<nb_e, 256, 0, stream>>>(src, dst, cursor, dinv, csrc, cw);

  // layer 1: t = x @ W1 ; h = agg(t) + b1   (relu deferred to next gemm read)
  k_gemm<0><<<nb_g, 256, 0, stream>>>(x, W1, tbuf);
  k_agg<<<nb_a, 256, 0, stream>>>(tbuf, rp, cnt, csrc, cw, dinv, b1, hbuf);
  // layer 2
  k_gemm<1><<<nb_g, 256, 0, stream>>>(hbuf, W2, tbuf);
  k_agg<<<nb_a, 256, 0, stream>>>(tbuf, rp, cnt, csrc, cw, dinv, b2, hbuf);
  // layer 3 -> n_emb straight into d_out
  k_gemm<1><<<nb_g, 256, 0, stream>>>(hbuf, W3, tbuf);
  k_agg<<<nb_a, 256, 0, stream>>>(tbuf, rp, cnt, csrc, cw, dinv, b3, nemb);
  // pool: 2-stage parallel reduction, then final linear
  k_pool1<<<NG * PCHUNK, 128, 0, stream>>>(nemb, batch, gsum);
  k_pool2<<<NG, 128, 0, stream>>>(gsum, batch, Wl, bl, gout);
}

// Round 3
// 445.566 us; speedup vs baseline: 1.5169x; 1.0977x over previous
//
#include <hip/hip_runtime.h>

#define NN 50000
#define NE 800000
#define CH 128
#define NG 64
#define OC 10

// ---------------- CSR build ----------------

__global__ __launch_bounds__(256) void k_zero(int* __restrict__ cnt, float* __restrict__ gsum) {
  int i = blockIdx.x * 256 + threadIdx.x;
  if (i < NN) cnt[i] = 0;
  if (i < NG * CH) gsum[i] = 0.f;
}

__global__ __launch_bounds__(256) void k_count(const int* __restrict__ dst, int* __restrict__ cnt) {
  int e = blockIdx.x * 256 + threadIdx.x;
  if (e < NE) atomicAdd(&cnt[dst[e]], 1);
}

__global__ __launch_bounds__(256) void k_dinv(const int* __restrict__ cnt, float* __restrict__ dinv) {
  int i = blockIdx.x * 256 + threadIdx.x;
  if (i < NN) dinv[i] = rsqrtf((float)(cnt[i] + 1));  // +1 = self loop; deg >= 1 always
}

__global__ __launch_bounds__(256) void k_scan1(const int* __restrict__ cnt, int* __restrict__ excl,
                                               int* __restrict__ bsum) {
  int t = threadIdx.x;
  int i = blockIdx.x * 256 + t;
  int v = (i < NN) ? cnt[i] : 0;
  __shared__ int s[256];
  s[t] = v;
  __syncthreads();
  for (int d = 1; d < 256; d <<= 1) {
    int x = (t >= d) ? s[t - d] : 0;
    __syncthreads();
    s[t] += x;
    __syncthreads();
  }
  if (i < NN) excl[i] = s[t] - v;
  if (t == 255) bsum[blockIdx.x] = s[255];
}

__global__ __launch_bounds__(256) void k_scan2(int* __restrict__ bsum, int nblocks) {
  int t = threadIdx.x;
  int v = (t < nblocks) ? bsum[t] : 0;
  __shared__ int s[256];
  s[t] = v;
  __syncthreads();
  for (int d = 1; d < 256; d <<= 1) {
    int x = (t >= d) ? s[t - d] : 0;
    __syncthreads();
    s[t] += x;
    __syncthreads();
  }
  if (t < nblocks) bsum[t] = s[t] - v;  // exclusive block offsets
}

__global__ __launch_bounds__(256) void k_scan3(int* __restrict__ rp, const int* __restrict__ bsum,
                                               int* __restrict__ cursor) {
  int i = blockIdx.x * 256 + threadIdx.x;
  if (i < NN) {
    int v = rp[i] + bsum[blockIdx.x];
    rp[i] = v;
    cursor[i] = v;
  }
}

__global__ __launch_bounds__(256) void k_fill(const int* __restrict__ src, const int* __restrict__ dst,
                                              int* __restrict__ cursor, int* __restrict__ csrc) {
  int e = blockIdx.x * 256 + threadIdx.x;
  if (e < NE) {
    int s = src[e], d = dst[e];
    int slot = atomicAdd(&cursor[d], 1);
    csrc[slot] = s;
  }
}

// ---------------- GEMM: T' = dinv * (f(A) @ W), A [NN][128], W [128][128] ----------------
// block = 256 thr (4 waves), 64 rows/block, thread = 8 rows x 4 cols.
// LDS: W chunk 64x128 (32 KB) + A tile 64x128 (32 KB) = 64 KB -> 2 blocks/CU.

__device__ inline void fma4(float4& acc, float a, const float4& w) {
  acc.x = fmaf(a, w.x, acc.x);
  acc.y = fmaf(a, w.y, acc.y);
  acc.z = fmaf(a, w.z, acc.z);
  acc.w = fmaf(a, w.w, acc.w);
}

template <int RELU>
__global__ __launch_bounds__(256) void k_gemm(const float* __restrict__ A, const float* __restrict__ W,
                                              const float* __restrict__ dinv, float* __restrict__ T) {
  __shared__ float4 sW[64 * 32];  // [k][c4]
  __shared__ float4 sA[64 * 32];  // [row][k4]
  const int t = threadIdx.x;
  const int brow = blockIdx.x * 64;

  // load A tile (coalesced float4), relu fused on read
#pragma unroll
  for (int i = 0; i < 8; ++i) {
    int f4 = t + i * 256;  // 0..2047
    int row = f4 >> 5, c4 = f4 & 31;
    float4 v = make_float4(0.f, 0.f, 0.f, 0.f);
    int gr = brow + row;
    if (gr < NN) v = ((const float4*)A)[gr * 32 + c4];
    if (RELU) {
      v.x = fmaxf(v.x, 0.f); v.y = fmaxf(v.y, 0.f);
      v.z = fmaxf(v.z, 0.f); v.w = fmaxf(v.w, 0.f);
    }
    sA[f4] = v;
  }

  float4 acc[8];
#pragma unroll
  for (int r = 0; r < 8; ++r) acc[r] = make_float4(0.f, 0.f, 0.f, 0.f);

  const int cl = t & 31;        // cols 4*cl..4*cl+3
  const int r0 = (t >> 5) * 8;  // 8 rows per thread

  for (int kc = 0; kc < 2; ++kc) {
    __syncthreads();  // protects sA stores (kc=0) and sW reuse (kc=1)
#pragma unroll
    for (int i = 0; i < 8; ++i) {
      int f4 = t + i * 256;  // 0..2047: k = f4>>5, c4 = f4&31
      sW[f4] = ((const float4*)W)[(kc * 64 + (f4 >> 5)) * 32 + (f4 & 31)];
    }
    __syncthreads();
#pragma unroll
    for (int k4 = 0; k4 < 16; ++k4) {
      float4 w0 = sW[(k4 * 4 + 0) * 32 + cl];
      float4 w1 = sW[(k4 * 4 + 1) * 32 + cl];
      float4 w2 = sW[(k4 * 4 + 2) * 32 + cl];
      float4 w3 = sW[(k4 * 4 + 3) * 32 + cl];
#pragma unroll
      for (int r = 0; r < 8; ++r) {
        float4 a4 = sA[(r0 + r) * 32 + kc * 16 + k4];
        fma4(acc[r], a4.x, w0);
        fma4(acc[r], a4.y, w1);
        fma4(acc[r], a4.z, w2);
        fma4(acc[r], a4.w, w3);
      }
    }
  }

#pragma unroll
  for (int r = 0; r < 8; ++r) {
    int gr = brow + r0 + r;
    if (gr < NN) {
      float d = dinv[gr];
      float4 v;
      v.x = acc[r].x * d; v.y = acc[r].y * d;
      v.z = acc[r].z * d; v.w = acc[r].w * d;
      ((float4*)T)[gr * 32 + cl] = v;
    }
  }
}

// ---------------- Aggregation: out[i] = b + dinv[i] * (T'[i] + sum_e T'[src_e]) ----------------
// one wave per node; two 32-lane halves, float4/lane covers full row; halves take
// alternate edges, unrolled x4 -> 8 concurrent 512B gathers per wave.

__global__ __launch_bounds__(256) void k_agg(const float* __restrict__ Tp, const int* __restrict__ rp,
                                             const int* __restrict__ cnt, const int* __restrict__ csrc,
                                             const float* __restrict__ dinv,
                                             const float* __restrict__ b, float* __restrict__ out) {
  const int node = blockIdx.x * 4 + (threadIdx.x >> 6);  // grid exact: 12500*4
  const int lane = threadIdx.x & 63;
  const int h = lane >> 5;    // half 0/1
  const int l32 = lane & 31;  // float4 slot -> channels 4*l32..4*l32+3
  const float4* T4 = (const float4*)Tp;

  float4 acc = make_float4(0.f, 0.f, 0.f, 0.f);
  if (h == 0) acc = T4[(size_t)node * 32 + l32];  // self term T'[node]

  const int beg = rp[node];
  const int num = cnt[node];
  int e = h;
  for (; e + 6 < num; e += 8) {
    int s0 = csrc[beg + e];
    int s1 = csrc[beg + e + 2];
    int s2 = csrc[beg + e + 4];
    int s3 = csrc[beg + e + 6];
    float4 m0 = T4[(size_t)s0 * 32 + l32];
    float4 m1 = T4[(size_t)s1 * 32 + l32];
    float4 m2 = T4[(size_t)s2 * 32 + l32];
    float4 m3 = T4[(size_t)s3 * 32 + l32];
    acc.x += m0.x + m1.x + m2.x + m3.x;
    acc.y += m0.y + m1.y + m2.y + m3.y;
    acc.z += m0.z + m1.z + m2.z + m3.z;
    acc.w += m0.w + m1.w + m2.w + m3.w;
  }
  for (; e < num; e += 2) {
    int s = csrc[beg + e];
    float4 m = T4[(size_t)s * 32 + l32];
    acc.x += m.x; acc.y += m.y; acc.z += m.z; acc.w += m.w;
  }

  // cross-half reduce (lane l and l+32 hold the same channels)
  acc.x += __shfl_xor(acc.x, 32);
  acc.y += __shfl_xor(acc.y, 32);
  acc.z += __shfl_xor(acc.z, 32);
  acc.w += __shfl_xor(acc.w, 32);

  if (h == 0) {
    float d = dinv[node];
    float4 bb = ((const float4*)b)[l32];
    float4 o;
    o.x = fmaf(d, acc.x, bb.x);
    o.y = fmaf(d, acc.y, bb.y);
    o.z = fmaf(d, acc.z, bb.z);
    o.w = fmaf(d, acc.w, bb.w);
    ((float4*)out)[(size_t)node * 32 + l32] = o;
  }
}

// ---------------- Pool (2-stage) + final linear ----------------

#define PCHUNK 32

__global__ __launch_bounds__(128) void k_pool1(const float* __restrict__ nemb,
                                               const int* __restrict__ batch,
                                               float* __restrict__ gsum) {
  int g = blockIdx.x >> 5;       // graph 0..63
  int ck = blockIdx.x & (PCHUNK - 1);
  int c = threadIdx.x;           // channel 0..127
  int lo = 0, hi = NN;
  while (lo < hi) { int m = (lo + hi) >> 1; if (batch[m] < g) lo = m + 1; else hi = m; }
  int beg = lo;
  hi = NN;
  while (lo < hi) { int m = (lo + hi) >> 1; if (batch[m] < g + 1) lo = m + 1; else hi = m; }
  int end = lo;
  int len = end - beg;
  int c0 = beg + (int)(((long long)len * ck) >> 5);
  int c1 = beg + (int)(((long long)len * (ck + 1)) >> 5);
  float sum = 0.f;
  for (int n = c0; n < c1; ++n) sum += nemb[(size_t)n * CH + c];
  atomicAdd(&gsum[g * CH + c], sum);
}

__global__ __launch_bounds__(128) void k_pool2(const float* __restrict__ gsum,
                                               const int* __restrict__ batch,
                                               const float* __restrict__ Wl,
                                               const float* __restrict__ bl,
                                               float* __restrict__ gout) {
  int g = blockIdx.x;
  int c = threadIdx.x;  // 0..127
  int lo = 0, hi = NN;
  while (lo < hi) { int m = (lo + hi) >> 1; if (batch[m] < g) lo = m + 1; else hi = m; }
  int beg = lo;
  hi = NN;
  while (lo < hi) { int m = (lo + hi) >> 1; if (batch[m] < g + 1) lo = m + 1; else hi = m; }
  int end = lo;
  float gv = gsum[g * CH + c] / fmaxf((float)(end - beg), 1.0f);

  __shared__ float sg[CH];
  sg[c] = gv;
  __syncthreads();
  if (c < OC) {
    float o = bl[c];
    for (int k = 0; k < CH; ++k) o = fmaf(sg[k], Wl[k * OC + c], o);
    gout[g * OC + c] = o;
  }
}

// ---------------- launch ----------------

extern "C" void kernel_launch(void* const* d_in, const int* in_sizes, int n_in,
                              void* d_out, int out_size, void* d_ws, size_t ws_size,
                              hipStream_t stream) {
  const float* x = (const float*)d_in[0];
  const int* ei = (const int*)d_in[1];
  const int* src = ei;
  const int* dst = ei + NE;
  const int* batch = (const int*)d_in[2];
  const float* W1 = (const float*)d_in[3];
  const float* b1 = (const float*)d_in[4];
  const float* W2 = (const float*)d_in[5];
  const float* b2 = (const float*)d_in[6];
  const float* W3 = (const float*)d_in[7];
  const float* b3 = (const float*)d_in[8];
  const float* Wl = (const float*)d_in[9];
  const float* bl = (const float*)d_in[10];

  char* ws = (char*)d_ws;
  size_t off = 0;
  auto alloc = [&](size_t bytes) {
    void* p = ws + off;
    off += (bytes + 255) & ~(size_t)255;
    return p;
  };
  int* cnt = (int*)alloc(NN * 4);
  float* dinv = (float*)alloc(NN * 4);
  int* rp = (int*)alloc(NN * 4);
  int* cursor = (int*)alloc(NN * 4);
  int* bsum = (int*)alloc(256 * 4);
  int* csrc = (int*)alloc((size_t)NE * 4);
  float* tbuf = (float*)alloc((size_t)NN * CH * 4);
  float* hbuf = (float*)alloc((size_t)NN * CH * 4);
  float* gsum = (float*)alloc((size_t)NG * CH * 4);

  float* gout = (float*)d_out;
  float* nemb = (float*)d_out + NG * OC;

  const int nb_n = (NN + 255) / 256;  // 196
  const int nb_e = (NE + 255) / 256;  // 3125
  const int nb_g = (NN + 63) / 64;    // 782
  const int nb_a = NN / 4;            // 12500

  k_zero<<<nb_n, 256, 0, stream>>>(cnt, gsum);
  k_count<<<nb_e, 256, 0, stream>>>(dst, cnt);
  k_dinv<<<nb_n, 256, 0, stream>>>(cnt, dinv);
  k_scan1<<<nb_n, 256, 0, stream>>>(cnt, rp, bsum);
  k_scan2<<<1, 256, 0, stream>>>(bsum, nb_n);
  k_scan3<<<nb_n, 256, 0, stream>>>(rp, bsum, cursor);
  k_fill<<<nb_e, 256, 0, stream>>>(src, dst, cursor, csrc);

  // layer 1: t' = dinv * (x @ W1) ; h = b1 + dinv*(t'[self] + sum t'[src])
  k_gemm<0><<<nb_g, 256, 0, stream>>>(x, W1, dinv, tbuf);
  k_agg<<<nb_a, 256, 0, stream>>>(tbuf, rp, cnt, csrc, dinv, b1, hbuf);
  // layer 2
  k_gemm<1><<<nb_g, 256, 0, stream>>>(hbuf, W2, dinv, tbuf);
  k_agg<<<nb_a, 256, 0, stream>>>(tbuf, rp, cnt, csrc, dinv, b2, hbuf);
  // layer 3 -> n_emb straight into d_out
  k_gemm<1><<<nb_g, 256, 0, stream>>>(hbuf, W3, dinv, tbuf);
  k_agg<<<nb_a, 256, 0, stream>>>(tbuf, rp, cnt, csrc, dinv, b3, nemb);
  // pool: 2-stage parallel reduction, then final linear
  k_pool1<<<NG * PCHUNK, 128, 0, stream>>>(nemb, batch, gsum);
  k_pool2<<<NG, 128, 0, stream>>>(gsum, batch, Wl, bl, gout);
}

// Round 4
// 356.187 us; speedup vs baseline: 1.8975x; 1.2509x over previous
//
#include <hip/hip_runtime.h>

#define NN 50000
#define NE 800000
#define CH 128
#define NG 64
#define OC 10

typedef __attribute__((ext_vector_type(8))) short bf16x8;
typedef __attribute__((ext_vector_type(4))) float f32x4;

// ---------------- CSR build ----------------

__global__ __launch_bounds__(256) void k_zero(int* __restrict__ cnt, float* __restrict__ gsum) {
  int i = blockIdx.x * 256 + threadIdx.x;
  if (i < NN) cnt[i] = 0;
  if (i < NG * CH) gsum[i] = 0.f;
}

__global__ __launch_bounds__(256) void k_count(const int* __restrict__ dst, int* __restrict__ cnt) {
  int e = blockIdx.x * 256 + threadIdx.x;
  if (e < NE) atomicAdd(&cnt[dst[e]], 1);
}

// scan over cnt -> exclusive prefix (block-local), block sums; also dinv = rsqrt(cnt+1)
__global__ __launch_bounds__(256) void k_scan1(const int* __restrict__ cnt, int* __restrict__ excl,
                                               int* __restrict__ bsum, float* __restrict__ dinv) {
  int t = threadIdx.x;
  int i = blockIdx.x * 256 + t;
  int v = (i < NN) ? cnt[i] : 0;
  if (i < NN) dinv[i] = rsqrtf((float)(v + 1));  // +1 self loop
  __shared__ int s[256];
  s[t] = v;
  __syncthreads();
  for (int d = 1; d < 256; d <<= 1) {
    int x = (t >= d) ? s[t - d] : 0;
    __syncthreads();
    s[t] += x;
    __syncthreads();
  }
  if (i < NN) excl[i] = s[t] - v;
  if (t == 255) bsum[blockIdx.x] = s[255];
}

__global__ __launch_bounds__(256) void k_scan2(int* __restrict__ bsum, int nblocks) {
  int t = threadIdx.x;
  int v = (t < nblocks) ? bsum[t] : 0;
  __shared__ int s[256];
  s[t] = v;
  __syncthreads();
  for (int d = 1; d < 256; d <<= 1) {
    int x = (t >= d) ? s[t - d] : 0;
    __syncthreads();
    s[t] += x;
    __syncthreads();
  }
  if (t < nblocks) bsum[t] = s[t] - v;
}

__global__ __launch_bounds__(256) void k_scan3(int* __restrict__ rp, const int* __restrict__ bsum,
                                               int* __restrict__ cursor) {
  int i = blockIdx.x * 256 + threadIdx.x;
  if (i < NN) {
    int v = rp[i] + bsum[blockIdx.x];
    rp[i] = v;
    cursor[i] = v;
  }
}

__global__ __launch_bounds__(256) void k_fill(const int* __restrict__ src, const int* __restrict__ dst,
                                              int* __restrict__ cursor, int* __restrict__ csrc) {
  int e = blockIdx.x * 256 + threadIdx.x;
  if (e < NE) {
    int s = src[e], d = dst[e];
    int slot = atomicAdd(&cursor[d], 1);
    csrc[slot] = s;
  }
}

// ---------------- bf16 split helpers ----------------

__device__ inline ushort f2bf_rne(float x) {
  union { float f; unsigned u; } c;
  c.f = x;
  unsigned r = c.u + 0x7FFFu + ((c.u >> 16) & 1u);
  return (ushort)(r >> 16);
}

// hi = truncate-to-bf16(x); lo = rne-bf16(x - hi). hi+lo ~= x to ~2^-17 rel.
__device__ inline void split_bf16(float x, ushort& hi, ushort& lo) {
  union { float f; unsigned u; } c;
  c.f = x;
  unsigned hb = c.u & 0xFFFF0000u;
  hi = (ushort)(hb >> 16);
  union { unsigned u; float f; } h;
  h.u = hb;
  lo = f2bf_rne(x - h.f);
}

// ---------------- W fragment prep: 3 layers, MFMA-fragment-ordered bf16 hi/lo ----------------
// frag index f = ks*8 + nt (ks: K-step of 32, nt: 16-col tile). lane l holds
// W[ks*32 + 8*(l>>4) + j][nt*16 + (l&15)], j=0..7, packed 8 bf16 = uint4.

__global__ __launch_bounds__(256) void k_prep(const float* __restrict__ W1, const float* __restrict__ W2,
                                              const float* __restrict__ W3, uint4* __restrict__ whf,
                                              uint4* __restrict__ wlf) {
  const float* W = (blockIdx.x == 0) ? W1 : (blockIdx.x == 1) ? W2 : W3;
  uint4* wh = whf + blockIdx.x * 2048;
  uint4* wl = wlf + blockIdx.x * 2048;
  for (int idx = threadIdx.x; idx < 2048; idx += 256) {
    int l = idx & 63, f = idx >> 6;
    int ks = f >> 3, nt = f & 7;
    int k0 = ks * 32 + (l >> 4) * 8;
    int col = nt * 16 + (l & 15);
    ushort h[8], lo[8];
#pragma unroll
    for (int j = 0; j < 8; ++j) split_bf16(W[(k0 + j) * CH + col], h[j], lo[j]);
    uint4 uh, ul;
    uh.x = (unsigned)h[0] | ((unsigned)h[1] << 16);
    uh.y = (unsigned)h[2] | ((unsigned)h[3] << 16);
    uh.z = (unsigned)h[4] | ((unsigned)h[5] << 16);
    uh.w = (unsigned)h[6] | ((unsigned)h[7] << 16);
    ul.x = (unsigned)lo[0] | ((unsigned)lo[1] << 16);
    ul.y = (unsigned)lo[2] | ((unsigned)lo[3] << 16);
    ul.z = (unsigned)lo[4] | ((unsigned)lo[5] << 16);
    ul.w = (unsigned)lo[6] | ((unsigned)lo[7] << 16);
    wh[idx] = uh;
    wl[idx] = ul;
  }
}

// ---------------- GEMM: T' = dinv * (f(A) @ W) via split-bf16 MFMA ----------------
// block = 256 thr (4 waves), 64 rows; wave w owns rows w*16..w*16+15, all 128 cols.
// acc = Ah@Wh + Al@Wh + Ah@Wl (fp32 MFMA accumulate), K=128 in 4 steps of 32.

template <int RELU>
__global__ __launch_bounds__(256) void k_gemm(const float* __restrict__ A, const uint4* __restrict__ whf,
                                              const uint4* __restrict__ wlf,
                                              const float* __restrict__ dinv, float* __restrict__ T) {
  __shared__ float sA[64][132];  // +16B row pad for bank spread (33.8 KB)
  const int t = threadIdx.x;
  const int brow = blockIdx.x * 64;

  // stage A tile, coalesced float4, relu fused
#pragma unroll
  for (int i = 0; i < 8; ++i) {
    int f4 = t + i * 256;  // 0..2047
    int row = f4 >> 5, c4 = f4 & 31;
    float4 v = make_float4(0.f, 0.f, 0.f, 0.f);
    int gr = brow + row;
    if (gr < NN) v = ((const float4*)A)[gr * 32 + c4];
    if (RELU) {
      v.x = fmaxf(v.x, 0.f); v.y = fmaxf(v.y, 0.f);
      v.z = fmaxf(v.z, 0.f); v.w = fmaxf(v.w, 0.f);
    }
    *(float4*)&sA[row][c4 * 4] = v;
  }
  __syncthreads();

  const int w = t >> 6;
  const int l = t & 63;
  const int lr = l & 15;   // A row within strip / D col within tile
  const int lk = l >> 4;   // K-chunk (8 wide) / D row group

  f32x4 acc[8];
#pragma unroll
  for (int nt = 0; nt < 8; ++nt) acc[nt] = (f32x4)(0.f);

#pragma unroll
  for (int ks = 0; ks < 4; ++ks) {
    const float* pa = &sA[w * 16 + lr][ks * 32 + lk * 8];
    float4 a0 = *(const float4*)pa;
    float4 a1 = *(const float4*)(pa + 4);
    float av[8] = {a0.x, a0.y, a0.z, a0.w, a1.x, a1.y, a1.z, a1.w};
    bf16x8 ah, al;
#pragma unroll
    for (int j = 0; j < 8; ++j) {
      ushort h, lo;
      split_bf16(av[j], h, lo);
      ah[j] = (short)h;
      al[j] = (short)lo;
    }
#pragma unroll
    for (int nt = 0; nt < 8; ++nt) {
      int fi = (ks * 8 + nt) * 64 + l;
      bf16x8 bh = ((const bf16x8*)whf)[fi];
      bf16x8 bl = ((const bf16x8*)wlf)[fi];
      acc[nt] = __builtin_amdgcn_mfma_f32_16x16x32_bf16(ah, bh, acc[nt], 0, 0, 0);
      acc[nt] = __builtin_amdgcn_mfma_f32_16x16x32_bf16(al, bh, acc[nt], 0, 0, 0);
      acc[nt] = __builtin_amdgcn_mfma_f32_16x16x32_bf16(ah, bl, acc[nt], 0, 0, 0);
    }
  }

  // epilogue: D row = lk*4+i, col = nt*16+lr; scale by dinv
#pragma unroll
  for (int i = 0; i < 4; ++i) {
    int grow = brow + w * 16 + lk * 4 + i;
    if (grow < NN) {
      float d = dinv[grow];
#pragma unroll
      for (int nt = 0; nt < 8; ++nt) {
        T[(size_t)grow * CH + nt * 16 + lr] = acc[nt][i] * d;
      }
    }
  }
}

// ---------------- Aggregation: out[i] = b + dinv[i] * (T'[i] + sum_e T'[src_e]) ----------------

__global__ __launch_bounds__(256) void k_agg(const float* __restrict__ Tp, const int* __restrict__ rp,
                                             const int* __restrict__ cnt, const int* __restrict__ csrc,
                                             const float* __restrict__ dinv,
                                             const float* __restrict__ b, float* __restrict__ out) {
  const int node = blockIdx.x * 4 + (threadIdx.x >> 6);  // grid exact: 12500*4
  const int lane = threadIdx.x & 63;
  const int h = lane >> 5;
  const int l32 = lane & 31;
  const float4* T4 = (const float4*)Tp;

  float4 acc = make_float4(0.f, 0.f, 0.f, 0.f);
  if (h == 0) acc = T4[(size_t)node * 32 + l32];  // self term

  const int beg = rp[node];
  const int num = cnt[node];
  int e = h;
  for (; e + 6 < num; e += 8) {
    int s0 = csrc[beg + e];
    int s1 = csrc[beg + e + 2];
    int s2 = csrc[beg + e + 4];
    int s3 = csrc[beg + e + 6];
    float4 m0 = T4[(size_t)s0 * 32 + l32];
    float4 m1 = T4[(size_t)s1 * 32 + l32];
    float4 m2 = T4[(size_t)s2 * 32 + l32];
    float4 m3 = T4[(size_t)s3 * 32 + l32];
    acc.x += m0.x + m1.x + m2.x + m3.x;
    acc.y += m0.y + m1.y + m2.y + m3.y;
    acc.z += m0.z + m1.z + m2.z + m3.z;
    acc.w += m0.w + m1.w + m2.w + m3.w;
  }
  for (; e < num; e += 2) {
    int s = csrc[beg + e];
    float4 m = T4[(size_t)s * 32 + l32];
    acc.x += m.x; acc.y += m.y; acc.z += m.z; acc.w += m.w;
  }

  acc.x += __shfl_xor(acc.x, 32);
  acc.y += __shfl_xor(acc.y, 32);
  acc.z += __shfl_xor(acc.z, 32);
  acc.w += __shfl_xor(acc.w, 32);

  if (h == 0) {
    float d = dinv[node];
    float4 bb = ((const float4*)b)[l32];
    float4 o;
    o.x = fmaf(d, acc.x, bb.x);
    o.y = fmaf(d, acc.y, bb.y);
    o.z = fmaf(d, acc.z, bb.z);
    o.w = fmaf(d, acc.w, bb.w);
    ((float4*)out)[(size_t)node * 32 + l32] = o;
  }
}

// ---------------- Pool (2-stage) + final linear ----------------

#define PCHUNK 32

__global__ __launch_bounds__(128) void k_pool1(const float* __restrict__ nemb,
                                               const int* __restrict__ batch,
                                               float* __restrict__ gsum) {
  int g = blockIdx.x >> 5;
  int ck = blockIdx.x & (PCHUNK - 1);
  int c = threadIdx.x;
  int lo = 0, hi = NN;
  while (lo < hi) { int m = (lo + hi) >> 1; if (batch[m] < g) lo = m + 1; else hi = m; }
  int beg = lo;
  hi = NN;
  while (lo < hi) { int m = (lo + hi) >> 1; if (batch[m] < g + 1) lo = m + 1; else hi = m; }
  int end = lo;
  int len = end - beg;
  int c0 = beg + (int)(((long long)len * ck) >> 5);
  int c1 = beg + (int)(((long long)len * (ck + 1)) >> 5);
  float sum = 0.f;
  for (int n = c0; n < c1; ++n) sum += nemb[(size_t)n * CH + c];
  atomicAdd(&gsum[g * CH + c], sum);
}

__global__ __launch_bounds__(128) void k_pool2(const float* __restrict__ gsum,
                                               const int* __restrict__ batch,
                                               const float* __restrict__ Wl,
                                               const float* __restrict__ bl,
                                               float* __restrict__ gout) {
  int g = blockIdx.x;
  int c = threadIdx.x;
  int lo = 0, hi = NN;
  while (lo < hi) { int m = (lo + hi) >> 1; if (batch[m] < g) lo = m + 1; else hi = m; }
  int beg = lo;
  hi = NN;
  while (lo < hi) { int m = (lo + hi) >> 1; if (batch[m] < g + 1) lo = m + 1; else hi = m; }
  int end = lo;
  float gv = gsum[g * CH + c] / fmaxf((float)(end - beg), 1.0f);

  __shared__ float sg[CH];
  sg[c] = gv;
  __syncthreads();
  if (c < OC) {
    float o = bl[c];
    for (int k = 0; k < CH; ++k) o = fmaf(sg[k], Wl[k * OC + c], o);
    gout[g * OC + c] = o;
  }
}

// ---------------- launch ----------------

extern "C" void kernel_launch(void* const* d_in, const int* in_sizes, int n_in,
                              void* d_out, int out_size, void* d_ws, size_t ws_size,
                              hipStream_t stream) {
  const float* x = (const float*)d_in[0];
  const int* ei = (const int*)d_in[1];
  const int* src = ei;
  const int* dst = ei + NE;
  const int* batch = (const int*)d_in[2];
  const float* W1 = (const float*)d_in[3];
  const float* b1 = (const float*)d_in[4];
  const float* W2 = (const float*)d_in[5];
  const float* b2 = (const float*)d_in[6];
  const float* W3 = (const float*)d_in[7];
  const float* b3 = (const float*)d_in[8];
  const float* Wl = (const float*)d_in[9];
  const float* bl = (const float*)d_in[10];

  char* ws = (char*)d_ws;
  size_t off = 0;
  auto alloc = [&](size_t bytes) {
    void* p = ws + off;
    off += (bytes + 255) & ~(size_t)255;
    return p;
  };
  int* cnt = (int*)alloc(NN * 4);
  float* dinv = (float*)alloc(NN * 4);
  int* rp = (int*)alloc(NN * 4);
  int* cursor = (int*)alloc(NN * 4);
  int* bsum = (int*)alloc(256 * 4);
  int* csrc = (int*)alloc((size_t)NE * 4);
  float* tbuf = (float*)alloc((size_t)NN * CH * 4);
  float* hbuf = (float*)alloc((size_t)NN * CH * 4);
  float* gsum = (float*)alloc((size_t)NG * CH * 4);
  uint4* whf = (uint4*)alloc(3 * 2048 * sizeof(uint4));  // 96 KB, frag-ordered Wh
  uint4* wlf = (uint4*)alloc(3 * 2048 * sizeof(uint4));  // 96 KB, frag-ordered Wl

  float* gout = (float*)d_out;
  float* nemb = (float*)d_out + NG * OC;

  const int nb_n = (NN + 255) / 256;  // 196
  const int nb_e = (NE + 255) / 256;  // 3125
  const int nb_g = (NN + 63) / 64;    // 782
  const int nb_a = NN / 4;            // 12500

  k_zero<<<nb_n, 256, 0, stream>>>(cnt, gsum);
  k_count<<<nb_e, 256, 0, stream>>>(dst, cnt);
  k_prep<<<3, 256, 0, stream>>>(W1, W2, W3, whf, wlf);
  k_scan1<<<nb_n, 256, 0, stream>>>(cnt, rp, bsum, dinv);
  k_scan2<<<1, 256, 0, stream>>>(bsum, nb_n);
  k_scan3<<<nb_n, 256, 0, stream>>>(rp, bsum, cursor);
  k_fill<<<nb_e, 256, 0, stream>>>(src, dst, cursor, csrc);

  // layer 1: t' = dinv * (x @ W1) ; h = b1 + dinv*(t'[self] + sum t'[src])
  k_gemm<0><<<nb_g, 256, 0, stream>>>(x, whf + 0 * 2048, wlf + 0 * 2048, dinv, tbuf);
  k_agg<<<nb_a, 256, 0, stream>>>(tbuf, rp, cnt, csrc, dinv, b1, hbuf);
  // layer 2
  k_gemm<1><<<nb_g, 256, 0, stream>>>(hbuf, whf + 1 * 2048, wlf + 1 * 2048, dinv, tbuf);
  k_agg<<<nb_a, 256, 0, stream>>>(tbuf, rp, cnt, csrc, dinv, b2, hbuf);
  // layer 3 -> n_emb straight into d_out
  k_gemm<1><<<nb_g, 256, 0, stream>>>(hbuf, whf + 2 * 2048, wlf + 2 * 2048, dinv, tbuf);
  k_agg<<<nb_a, 256, 0, stream>>>(tbuf, rp, cnt, csrc, dinv, b3, nemb);
  // pool
  k_pool1<<<NG * PCHUNK, 128, 0, stream>>>(nemb, batch, gsum);
  k_pool2<<<NG, 128, 0, stream>>>(gsum, batch, Wl, bl, gout);
}

// Round 5
// 284.540 us; speedup vs baseline: 2.3753x; 1.2518x over previous
//
#include <hip/hip_runtime.h>
#include <hip/hip_fp16.h>

#define NN 50000
#define NE 800000
#define CH 128
#define NG 64
#define OC 10

typedef _Float16 f16x8 __attribute__((ext_vector_type(8)));
typedef float f32x4 __attribute__((ext_vector_type(4)));

__device__ inline ushort f2h(float x) { __half h = __float2half(x); return __half_as_ushort(h); }
__device__ inline float h2f(ushort u) { return __half2float(__ushort_as_half(u)); }

// ---------------- CSR build ----------------

__global__ __launch_bounds__(256) void k_zero(int* __restrict__ cnt, float* __restrict__ gsum) {
  int i = blockIdx.x * 256 + threadIdx.x;
  if (i < NN) cnt[i] = 0;
  if (i < NG * CH) gsum[i] = 0.f;
}

__global__ __launch_bounds__(256) void k_count(const int* __restrict__ dst, int* __restrict__ cnt) {
  int e = blockIdx.x * 256 + threadIdx.x;
  if (e < NE) atomicAdd(&cnt[dst[e]], 1);
}

__global__ __launch_bounds__(256) void k_scan1(const int* __restrict__ cnt, int* __restrict__ excl,
                                               int* __restrict__ bsum, float* __restrict__ dinv) {
  int t = threadIdx.x;
  int i = blockIdx.x * 256 + t;
  int v = (i < NN) ? cnt[i] : 0;
  if (i < NN) dinv[i] = rsqrtf((float)(v + 1));  // +1 self loop
  __shared__ int s[256];
  s[t] = v;
  __syncthreads();
  for (int d = 1; d < 256; d <<= 1) {
    int x = (t >= d) ? s[t - d] : 0;
    __syncthreads();
    s[t] += x;
    __syncthreads();
  }
  if (i < NN) excl[i] = s[t] - v;
  if (t == 255) bsum[blockIdx.x] = s[255];
}

__global__ __launch_bounds__(256) void k_scan2(int* __restrict__ bsum, int nblocks) {
  int t = threadIdx.x;
  int v = (t < nblocks) ? bsum[t] : 0;
  __shared__ int s[256];
  s[t] = v;
  __syncthreads();
  for (int d = 1; d < 256; d <<= 1) {
    int x = (t >= d) ? s[t - d] : 0;
    __syncthreads();
    s[t] += x;
    __syncthreads();
  }
  if (t < nblocks) bsum[t] = s[t] - v;
}

__global__ __launch_bounds__(256) void k_scan3(int* __restrict__ rp, const int* __restrict__ bsum,
                                               int* __restrict__ cursor) {
  int i = blockIdx.x * 256 + threadIdx.x;
  if (i < NN) {
    int v = rp[i] + bsum[blockIdx.x];
    rp[i] = v;
    cursor[i] = v;
  }
}

__global__ __launch_bounds__(256) void k_fill(const int* __restrict__ src, const int* __restrict__ dst,
                                              int* __restrict__ cursor, int* __restrict__ csrc) {
  int e = blockIdx.x * 256 + threadIdx.x;
  if (e < NE) {
    int s = src[e], d = dst[e];
    int slot = atomicAdd(&cursor[d], 1);
    csrc[slot] = s;
  }
}

// ---------------- W fragment prep: fp16, MFMA-fragment-ordered ----------------
// frag f = ks*8 + nt. lane l holds W[ks*32 + 8*(l>>4) + j][nt*16 + (l&15)], j=0..7.

__global__ __launch_bounds__(256) void k_prep(const float* __restrict__ W1, const float* __restrict__ W2,
                                              const float* __restrict__ W3, uint4* __restrict__ whf) {
  const float* W = (blockIdx.x == 0) ? W1 : (blockIdx.x == 1) ? W2 : W3;
  uint4* wh = whf + blockIdx.x * 2048;
  for (int idx = threadIdx.x; idx < 2048; idx += 256) {
    int l = idx & 63, f = idx >> 6;
    int ks = f >> 3, nt = f & 7;
    int k0 = ks * 32 + (l >> 4) * 8;
    int col = nt * 16 + (l & 15);
    ushort h[8];
#pragma unroll
    for (int j = 0; j < 8; ++j) h[j] = f2h(W[(k0 + j) * CH + col]);
    uint4 u;
    u.x = (unsigned)h[0] | ((unsigned)h[1] << 16);
    u.y = (unsigned)h[2] | ((unsigned)h[3] << 16);
    u.z = (unsigned)h[4] | ((unsigned)h[5] << 16);
    u.w = (unsigned)h[6] | ((unsigned)h[7] << 16);
    wh[idx] = u;
  }
}

// ---------------- GEMM: T' = dinv * (A @ W) via fp16 MFMA, T stored fp16 ----------------
// block = 256 thr (4 waves), 64 rows; wave w owns rows w*16..w*16+15, all 128 cols.
// LDS A tile fp16 [64][128] with XOR swizzle (ushort idx ^= (row&7)<<3).
// IN_HALF=0: A fp32 (layer 1, x). IN_HALF=1: A fp16 (h, already relu'd by agg).

template <int IN_HALF>
__global__ __launch_bounds__(256) void k_gemm(const float* __restrict__ Af, const ushort* __restrict__ Ah,
                                              const uint4* __restrict__ whf,
                                              const float* __restrict__ dinv, ushort* __restrict__ T) {
  __shared__ ushort sA[64 * 128];  // 16 KB
  const int t = threadIdx.x;
  const int brow = blockIdx.x * 64;

  if (IN_HALF) {
    // 1024 chunks of 16 B (8 fp16); coalesced
#pragma unroll
    for (int i = 0; i < 4; ++i) {
      int id = t + i * 256;
      int row = id >> 4, c16 = id & 15;
      int gr = brow + row;
      uint4 u = make_uint4(0, 0, 0, 0);
      if (gr < NN) u = ((const uint4*)Ah)[gr * 16 + c16];
      int idx = (row * 128 + c16 * 8) ^ ((row & 7) << 3);
      *(uint4*)&sA[idx] = u;
    }
  } else {
    // 2048 chunks: load float4 (4 ch), cvt -> 4 fp16 (8 B); coalesced
#pragma unroll
    for (int i = 0; i < 8; ++i) {
      int id = t + i * 256;
      int row = id >> 5, c8 = id & 31;
      int gr = brow + row;
      float4 v = make_float4(0.f, 0.f, 0.f, 0.f);
      if (gr < NN) v = ((const float4*)Af)[gr * 32 + c8];
      ushort4 p;
      p.x = f2h(v.x); p.y = f2h(v.y); p.z = f2h(v.z); p.w = f2h(v.w);
      int idx = (row * 128 + c8 * 4) ^ ((row & 7) << 3);
      *(ushort4*)&sA[idx] = p;
    }
  }
  __syncthreads();

  const int w = t >> 6;
  const int l = t & 63;
  const int lr = l & 15;   // A row in strip / D col in tile
  const int lk = l >> 4;   // K-chunk / D row group
  const int arow = w * 16 + lr;

  // prefetch all 4 A-fragments (64 B)
  f16x8 afr[4];
#pragma unroll
  for (int ks = 0; ks < 4; ++ks) {
    int idx = (arow * 128 + ks * 32 + lk * 8) ^ ((arow & 7) << 3);
    afr[ks] = __builtin_bit_cast(f16x8, *(const uint4*)&sA[idx]);
  }

  f32x4 acc[8];
#pragma unroll
  for (int nt = 0; nt < 8; ++nt) acc[nt] = (f32x4)(0.f);

#pragma unroll
  for (int ks = 0; ks < 4; ++ks) {
#pragma unroll
    for (int nt = 0; nt < 8; ++nt) {
      f16x8 bh = __builtin_bit_cast(f16x8, whf[(ks * 8 + nt) * 64 + l]);
      acc[nt] = __builtin_amdgcn_mfma_f32_16x16x32_f16(afr[ks], bh, acc[nt], 0, 0, 0);
    }
  }

  // epilogue: D row = w*16 + lk*4 + i, col = nt*16 + lr; scale by dinv, store fp16
#pragma unroll
  for (int i = 0; i < 4; ++i) {
    int grow = brow + w * 16 + lk * 4 + i;
    if (grow < NN) {
      float d = dinv[grow];
#pragma unroll
      for (int nt = 0; nt < 8; ++nt) {
        T[(size_t)grow * CH + nt * 16 + lr] = f2h(acc[nt][i] * d);
      }
    }
  }
}

// ---------------- Aggregation: out[i] = b + dinv[i] * (T'[i] + sum_e T'[src_e]) ----------------
// T' is fp16 [NN][128]; one wave per node, two 32-lane halves on alternate edges,
// ushort4 (8 B = 4 ch) per lane -> 256 B per row gather, unroll x4 -> 8 in flight.
// MODE 0: out = fp16 relu(...) (feeds next GEMM). MODE 1: out = fp32 (n_emb).

template <int MODE>
__global__ __launch_bounds__(256) void k_agg(const ushort* __restrict__ Tp, const int* __restrict__ rp,
                                             const int* __restrict__ cnt, const int* __restrict__ csrc,
                                             const float* __restrict__ dinv, const float* __restrict__ b,
                                             ushort* __restrict__ outh, float* __restrict__ outf) {
  const int node = blockIdx.x * 4 + (threadIdx.x >> 6);  // grid exact: 12500*4
  const int lane = threadIdx.x & 63;
  const int h = lane >> 5;
  const int l32 = lane & 31;
  const ushort4* T4 = (const ushort4*)Tp;  // row = 32 ushort4

  float4 acc = make_float4(0.f, 0.f, 0.f, 0.f);
  if (h == 0) {
    ushort4 tv = T4[(size_t)node * 32 + l32];  // self term
    acc.x = h2f(tv.x); acc.y = h2f(tv.y); acc.z = h2f(tv.z); acc.w = h2f(tv.w);
  }

  const int beg = rp[node];
  const int num = cnt[node];
  int e = h;
  for (; e + 6 < num; e += 8) {
    int s0 = csrc[beg + e];
    int s1 = csrc[beg + e + 2];
    int s2 = csrc[beg + e + 4];
    int s3 = csrc[beg + e + 6];
    ushort4 m0 = T4[(size_t)s0 * 32 + l32];
    ushort4 m1 = T4[(size_t)s1 * 32 + l32];
    ushort4 m2 = T4[(size_t)s2 * 32 + l32];
    ushort4 m3 = T4[(size_t)s3 * 32 + l32];
    acc.x += (h2f(m0.x) + h2f(m1.x)) + (h2f(m2.x) + h2f(m3.x));
    acc.y += (h2f(m0.y) + h2f(m1.y)) + (h2f(m2.y) + h2f(m3.y));
    acc.z += (h2f(m0.z) + h2f(m1.z)) + (h2f(m2.z) + h2f(m3.z));
    acc.w += (h2f(m0.w) + h2f(m1.w)) + (h2f(m2.w) + h2f(m3.w));
  }
  for (; e < num; e += 2) {
    int s = csrc[beg + e];
    ushort4 m = T4[(size_t)s * 32 + l32];
    acc.x += h2f(m.x); acc.y += h2f(m.y); acc.z += h2f(m.z); acc.w += h2f(m.w);
  }

  acc.x += __shfl_xor(acc.x, 32);
  acc.y += __shfl_xor(acc.y, 32);
  acc.z += __shfl_xor(acc.z, 32);
  acc.w += __shfl_xor(acc.w, 32);

  if (h == 0) {
    float d = dinv[node];
    float4 bb = ((const float4*)b)[l32];
    float4 o;
    o.x = fmaf(d, acc.x, bb.x);
    o.y = fmaf(d, acc.y, bb.y);
    o.z = fmaf(d, acc.z, bb.z);
    o.w = fmaf(d, acc.w, bb.w);
    if (MODE == 0) {
      ushort4 p;
      p.x = f2h(fmaxf(o.x, 0.f)); p.y = f2h(fmaxf(o.y, 0.f));
      p.z = f2h(fmaxf(o.z, 0.f)); p.w = f2h(fmaxf(o.w, 0.f));
      ((ushort4*)outh)[(size_t)node * 32 + l32] = p;
    } else {
      ((float4*)outf)[(size_t)node * 32 + l32] = o;
    }
  }
}

// ---------------- Pool (2-stage) + final linear ----------------

#define PCHUNK 32

__global__ __launch_bounds__(128) void k_pool1(const float* __restrict__ nemb,
                                               const int* __restrict__ batch,
                                               float* __restrict__ gsum) {
  int g = blockIdx.x >> 5;
  int ck = blockIdx.x & (PCHUNK - 1);
  int c = threadIdx.x;
  int lo = 0, hi = NN;
  while (lo < hi) { int m = (lo + hi) >> 1; if (batch[m] < g) lo = m + 1; else hi = m; }
  int beg = lo;
  hi = NN;
  while (lo < hi) { int m = (lo + hi) >> 1; if (batch[m] < g + 1) lo = m + 1; else hi = m; }
  int end = lo;
  int len = end - beg;
  int c0 = beg + (int)(((long long)len * ck) >> 5);
  int c1 = beg + (int)(((long long)len * (ck + 1)) >> 5);
  float sum = 0.f;
  for (int n = c0; n < c1; ++n) sum += nemb[(size_t)n * CH + c];
  atomicAdd(&gsum[g * CH + c], sum);
}

__global__ __launch_bounds__(128) void k_pool2(const float* __restrict__ gsum,
                                               const int* __restrict__ batch,
                                               const float* __restrict__ Wl,
                                               const float* __restrict__ bl,
                                               float* __restrict__ gout) {
  int g = blockIdx.x;
  int c = threadIdx.x;
  int lo = 0, hi = NN;
  while (lo < hi) { int m = (lo + hi) >> 1; if (batch[m] < g) lo = m + 1; else hi = m; }
  int beg = lo;
  hi = NN;
  while (lo < hi) { int m = (lo + hi) >> 1; if (batch[m] < g + 1) lo = m + 1; else hi = m; }
  int end = lo;
  float gv = gsum[g * CH + c] / fmaxf((float)(end - beg), 1.0f);

  __shared__ float sg[CH];
  sg[c] = gv;
  __syncthreads();
  if (c < OC) {
    float o = bl[c];
    for (int k = 0; k < CH; ++k) o = fmaf(sg[k], Wl[k * OC + c], o);
    gout[g * OC + c] = o;
  }
}

// ---------------- launch ----------------

extern "C" void kernel_launch(void* const* d_in, const int* in_sizes, int n_in,
                              void* d_out, int out_size, void* d_ws, size_t ws_size,
                              hipStream_t stream) {
  const float* x = (const float*)d_in[0];
  const int* ei = (const int*)d_in[1];
  const int* src = ei;
  const int* dst = ei + NE;
  const int* batch = (const int*)d_in[2];
  const float* W1 = (const float*)d_in[3];
  const float* b1 = (const float*)d_in[4];
  const float* W2 = (const float*)d_in[5];
  const float* b2 = (const float*)d_in[6];
  const float* W3 = (const float*)d_in[7];
  const float* b3 = (const float*)d_in[8];
  const float* Wl = (const float*)d_in[9];
  const float* bl = (const float*)d_in[10];

  char* ws = (char*)d_ws;
  size_t off = 0;
  auto alloc = [&](size_t bytes) {
    void* p = ws + off;
    off += (bytes + 255) & ~(size_t)255;
    return p;
  };
  int* cnt = (int*)alloc(NN * 4);
  float* dinv = (float*)alloc(NN * 4);
  int* rp = (int*)alloc(NN * 4);
  int* cursor = (int*)alloc(NN * 4);
  int* bsum = (int*)alloc(256 * 4);
  int* csrc = (int*)alloc((size_t)NE * 4);
  ushort* thalf = (ushort*)alloc((size_t)NN * CH * 2);  // T' fp16
  ushort* hhalf = (ushort*)alloc((size_t)NN * CH * 2);  // h fp16 (relu'd)
  float* gsum = (float*)alloc((size_t)NG * CH * 4);
  uint4* whf = (uint4*)alloc(3 * 2048 * sizeof(uint4));  // 96 KB fp16 W frags

  float* gout = (float*)d_out;
  float* nemb = (float*)d_out + NG * OC;

  const int nb_n = (NN + 255) / 256;  // 196
  const int nb_e = (NE + 255) / 256;  // 3125
  const int nb_g = (NN + 63) / 64;    // 782
  const int nb_a = NN / 4;            // 12500

  k_zero<<<nb_n, 256, 0, stream>>>(cnt, gsum);
  k_count<<<nb_e, 256, 0, stream>>>(dst, cnt);
  k_prep<<<3, 256, 0, stream>>>(W1, W2, W3, whf);
  k_scan1<<<nb_n, 256, 0, stream>>>(cnt, rp, bsum, dinv);
  k_scan2<<<1, 256, 0, stream>>>(bsum, nb_n);
  k_scan3<<<nb_n, 256, 0, stream>>>(rp, bsum, cursor);
  k_fill<<<nb_e, 256, 0, stream>>>(src, dst, cursor, csrc);

  // layer 1: T' = dinv*(x @ W1); h = relu(b1 + dinv*(T'self + sum T'src)) -> fp16
  k_gemm<0><<<nb_g, 256, 0, stream>>>(x, nullptr, whf + 0 * 2048, dinv, thalf);
  k_agg<0><<<nb_a, 256, 0, stream>>>(thalf, rp, cnt, csrc, dinv, b1, hhalf, nullptr);
  // layer 2
  k_gemm<1><<<nb_g, 256, 0, stream>>>(nullptr, hhalf, whf + 1 * 2048, dinv, thalf);
  k_agg<0><<<nb_a, 256, 0, stream>>>(thalf, rp, cnt, csrc, dinv, b2, hhalf, nullptr);
  // layer 3 -> n_emb fp32 straight into d_out (no relu)
  k_gemm<1><<<nb_g, 256, 0, stream>>>(nullptr, hhalf, whf + 2 * 2048, dinv, thalf);
  k_agg<1><<<nb_a, 256, 0, stream>>>(thalf, rp, cnt, csrc, dinv, b3, nullptr, nemb);
  // pool
  k_pool1<<<NG * PCHUNK, 128, 0, stream>>>(nemb, batch, gsum);
  k_pool2<<<NG, 128, 0, stream>>>(gsum, batch, Wl, bl, gout);
}

// Round 6
// 217.579 us; speedup vs baseline: 3.1064x; 1.3078x over previous
//
#include <hip/hip_runtime.h>
#include <hip/hip_fp16.h>

#define NN 50000
#define NE 800000
#define CH 128
#define NG 64
#define OC 10

#define NB 196        // ceil(50000/256) coarse buckets of 256 nodes
#define TILE 4096     // edges per k_bin tile
#define PCAP 8192     // pbuf slots per bucket (avg fill 4096, +64 sigma headroom)

typedef _Float16 f16x8 __attribute__((ext_vector_type(8)));
typedef float f32x4 __attribute__((ext_vector_type(4)));

__device__ inline ushort f2h(float x) { __half h = __float2half(x); return __half_as_ushort(h); }
__device__ inline float h2f(ushort u) { return __half2float(__ushort_as_half(u)); }

// ---------------- init ----------------

__global__ __launch_bounds__(256) void k_zero(int* __restrict__ gcur, float* __restrict__ gsum) {
  int i = blockIdx.x * 256 + threadIdx.x;
  if (i < NB) gcur[i] = 0;
  if (i < NG * CH) gsum[i] = 0.f;
}

// ---------------- pass 1: bin edges into 196 coarse buckets, LDS-staged ----------------
// bucket b = dst>>8. pbuf[b*PCAP + slot] = (src,dst). gcur[b] ends as bucket length.

__global__ __launch_bounds__(256) void k_bin(const int* __restrict__ src, const int* __restrict__ dst,
                                             int* __restrict__ gcur, uint2* __restrict__ pbuf) {
  __shared__ int scnt[NB];            // per-tile bucket counts, then cursors
  __shared__ int soff[NB];            // exclusive offsets
  __shared__ int gbase[NB];           // reserved global base per bucket
  __shared__ int ssc[256];            // scan scratch
  __shared__ uint2 pairs[TILE];       // bucket-ordered staging
  __shared__ unsigned char bid[TILE]; // bucket id per staged slot
  const int t = threadIdx.x;

  for (int tile0 = blockIdx.x * TILE; tile0 < NE; tile0 += gridDim.x * TILE) {
    const int tcount = min(TILE, NE - tile0);
    for (int i = t; i < NB; i += 256) scnt[i] = 0;
    __syncthreads();
    // count
    for (int i = t; i < tcount; i += 256) {
      int d = dst[tile0 + i];
      atomicAdd(&scnt[d >> 8], 1);
    }
    __syncthreads();
    // block scan of NB counts -> soff (exclusive)
    int v = (t < NB) ? scnt[t] : 0;
    ssc[t] = v;
    __syncthreads();
    for (int d2 = 1; d2 < 256; d2 <<= 1) {
      int x2 = (t >= d2) ? ssc[t - d2] : 0;
      __syncthreads();
      ssc[t] += x2;
      __syncthreads();
    }
    if (t < NB) {
      soff[t] = ssc[t] - v;
      gbase[t] = (v > 0) ? atomicAdd(&gcur[t], v) : 0;  // reserve global span
      scnt[t] = ssc[t] - v;                             // reuse as cursor
    }
    __syncthreads();
    // scatter pairs into LDS, bucket-ordered
    for (int i = t; i < tcount; i += 256) {
      int s = src[tile0 + i], d = dst[tile0 + i];
      int b = d >> 8;
      int pos = atomicAdd(&scnt[b], 1);
      pairs[pos] = make_uint2((unsigned)s, (unsigned)d);
      bid[pos] = (unsigned char)b;
    }
    __syncthreads();
    // linear copy-out: consecutive threads -> consecutive addresses per segment
    for (int i = t; i < tcount; i += 256) {
      int b = bid[i];
      pbuf[((size_t)b << 13) + gbase[b] + (i - soff[b])] = pairs[i];
    }
    __syncthreads();
  }
}

// ---------------- bucket-base scan: bstart[b] = csrc offset of bucket b ----------------

__global__ __launch_bounds__(256) void k_bscan(const int* __restrict__ gcur, int* __restrict__ bstart) {
  int t = threadIdx.x;
  int v = (t < NB) ? gcur[t] : 0;
  __shared__ int s[256];
  s[t] = v;
  __syncthreads();
  for (int d = 1; d < 256; d <<= 1) {
    int x = (t >= d) ? s[t - d] : 0;
    __syncthreads();
    s[t] += x;
    __syncthreads();
  }
  if (t < NB) bstart[t] = s[t] - v;
  if (t == 255) bstart[NB] = s[255];  // = NE
}

// ---------------- pass 2: per-bucket fill -> csrc, cnt, rp, dinv ----------------
// one block per bucket; all global writes either coalesced or confined to the
// bucket's own <=32KB csrc window (single block -> no cross-XCD line bounce).

__global__ __launch_bounds__(256) void k_fill2(const uint2* __restrict__ pbuf, const int* __restrict__ gcur,
                                               const int* __restrict__ bstart, int* __restrict__ csrc,
                                               int* __restrict__ cnt, int* __restrict__ rp,
                                               float* __restrict__ dinv) {
  __shared__ int lcnt[256], loff[256], lcur[256], ssc[256];
  const int b = blockIdx.x;
  const int t = threadIdx.x;
  const int n0 = b * 256;
  const int nn = min(256, NN - n0);
  const int beg = bstart[b];
  const int len = gcur[b];
  const uint2* pb = pbuf + ((size_t)b << 13);

  lcnt[t] = 0;
  __syncthreads();
  for (int i = t; i < len; i += 256) {
    atomicAdd(&lcnt[pb[i].y & 255], 1);
  }
  __syncthreads();
  int v = lcnt[t];
  ssc[t] = v;
  __syncthreads();
  for (int d = 1; d < 256; d <<= 1) {
    int x = (t >= d) ? ssc[t - d] : 0;
    __syncthreads();
    ssc[t] += x;
    __syncthreads();
  }
  loff[t] = ssc[t] - v;
  lcur[t] = ssc[t] - v;
  if (t < nn) {
    cnt[n0 + t] = v;
    rp[n0 + t] = beg + loff[t];
    dinv[n0 + t] = rsqrtf((float)(v + 1));  // +1 self loop
  }
  __syncthreads();
  for (int i = t; i < len; i += 256) {
    uint2 p = pb[i];
    int slot = atomicAdd(&lcur[p.y & 255], 1);
    csrc[beg + slot] = (int)p.x;
  }
}

// ---------------- W fragment prep: fp16, MFMA-fragment-ordered ----------------

__global__ __launch_bounds__(256) void k_prep(const float* __restrict__ W1, const float* __restrict__ W2,
                                              const float* __restrict__ W3, uint4* __restrict__ whf) {
  const float* W = (blockIdx.x == 0) ? W1 : (blockIdx.x == 1) ? W2 : W3;
  uint4* wh = whf + blockIdx.x * 2048;
  for (int idx = threadIdx.x; idx < 2048; idx += 256) {
    int l = idx & 63, f = idx >> 6;
    int ks = f >> 3, nt = f & 7;
    int k0 = ks * 32 + (l >> 4) * 8;
    int col = nt * 16 + (l & 15);
    ushort h[8];
#pragma unroll
    for (int j = 0; j < 8; ++j) h[j] = f2h(W[(k0 + j) * CH + col]);
    uint4 u;
    u.x = (unsigned)h[0] | ((unsigned)h[1] << 16);
    u.y = (unsigned)h[2] | ((unsigned)h[3] << 16);
    u.z = (unsigned)h[4] | ((unsigned)h[5] << 16);
    u.w = (unsigned)h[6] | ((unsigned)h[7] << 16);
    wh[idx] = u;
  }
}

// ---------------- GEMM: T' = dinv * (A @ W) via fp16 MFMA, T stored fp16 ----------------

template <int IN_HALF>
__global__ __launch_bounds__(256) void k_gemm(const float* __restrict__ Af, const ushort* __restrict__ Ah,
                                              const uint4* __restrict__ whf,
                                              const float* __restrict__ dinv, ushort* __restrict__ T) {
  __shared__ ushort sA[64 * 128];  // 16 KB
  const int t = threadIdx.x;
  const int brow = blockIdx.x * 64;

  if (IN_HALF) {
#pragma unroll
    for (int i = 0; i < 4; ++i) {
      int id = t + i * 256;
      int row = id >> 4, c16 = id & 15;
      int gr = brow + row;
      uint4 u = make_uint4(0, 0, 0, 0);
      if (gr < NN) u = ((const uint4*)Ah)[gr * 16 + c16];
      int idx = (row * 128 + c16 * 8) ^ ((row & 7) << 3);
      *(uint4*)&sA[idx] = u;
    }
  } else {
#pragma unroll
    for (int i = 0; i < 8; ++i) {
      int id = t + i * 256;
      int row = id >> 5, c8 = id & 31;
      int gr = brow + row;
      float4 v = make_float4(0.f, 0.f, 0.f, 0.f);
      if (gr < NN) v = ((const float4*)Af)[gr * 32 + c8];
      ushort4 p;
      p.x = f2h(v.x); p.y = f2h(v.y); p.z = f2h(v.z); p.w = f2h(v.w);
      int idx = (row * 128 + c8 * 4) ^ ((row & 7) << 3);
      *(ushort4*)&sA[idx] = p;
    }
  }
  __syncthreads();

  const int w = t >> 6;
  const int l = t & 63;
  const int lr = l & 15;
  const int lk = l >> 4;
  const int arow = w * 16 + lr;

  f16x8 afr[4];
#pragma unroll
  for (int ks = 0; ks < 4; ++ks) {
    int idx = (arow * 128 + ks * 32 + lk * 8) ^ ((arow & 7) << 3);
    afr[ks] = __builtin_bit_cast(f16x8, *(const uint4*)&sA[idx]);
  }

  f32x4 acc[8];
#pragma unroll
  for (int nt = 0; nt < 8; ++nt) acc[nt] = (f32x4)(0.f);

#pragma unroll
  for (int ks = 0; ks < 4; ++ks) {
#pragma unroll
    for (int nt = 0; nt < 8; ++nt) {
      f16x8 bh = __builtin_bit_cast(f16x8, whf[(ks * 8 + nt) * 64 + l]);
      acc[nt] = __builtin_amdgcn_mfma_f32_16x16x32_f16(afr[ks], bh, acc[nt], 0, 0, 0);
    }
  }

#pragma unroll
  for (int i = 0; i < 4; ++i) {
    int grow = brow + w * 16 + lk * 4 + i;
    if (grow < NN) {
      float d = dinv[grow];
#pragma unroll
      for (int nt = 0; nt < 8; ++nt) {
        T[(size_t)grow * CH + nt * 16 + lr] = f2h(acc[nt][i] * d);
      }
    }
  }
}

// ---------------- Aggregation ----------------

template <int MODE>
__global__ __launch_bounds__(256) void k_agg(const ushort* __restrict__ Tp, const int* __restrict__ rp,
                                             const int* __restrict__ cnt, const int* __restrict__ csrc,
                                             const float* __restrict__ dinv, const float* __restrict__ b,
                                             ushort* __restrict__ outh, float* __restrict__ outf) {
  const int node = blockIdx.x * 4 + (threadIdx.x >> 6);
  const int lane = threadIdx.x & 63;
  const int h = lane >> 5;
  const int l32 = lane & 31;
  const ushort4* T4 = (const ushort4*)Tp;

  float4 acc = make_float4(0.f, 0.f, 0.f, 0.f);
  if (h == 0) {
    ushort4 tv = T4[(size_t)node * 32 + l32];
    acc.x = h2f(tv.x); acc.y = h2f(tv.y); acc.z = h2f(tv.z); acc.w = h2f(tv.w);
  }

  const int beg = rp[node];
  const int num = cnt[node];
  int e = h;
  for (; e + 6 < num; e += 8) {
    int s0 = csrc[beg + e];
    int s1 = csrc[beg + e + 2];
    int s2 = csrc[beg + e + 4];
    int s3 = csrc[beg + e + 6];
    ushort4 m0 = T4[(size_t)s0 * 32 + l32];
    ushort4 m1 = T4[(size_t)s1 * 32 + l32];
    ushort4 m2 = T4[(size_t)s2 * 32 + l32];
    ushort4 m3 = T4[(size_t)s3 * 32 + l32];
    acc.x += (h2f(m0.x) + h2f(m1.x)) + (h2f(m2.x) + h2f(m3.x));
    acc.y += (h2f(m0.y) + h2f(m1.y)) + (h2f(m2.y) + h2f(m3.y));
    acc.z += (h2f(m0.z) + h2f(m1.z)) + (h2f(m2.z) + h2f(m3.z));
    acc.w += (h2f(m0.w) + h2f(m1.w)) + (h2f(m2.w) + h2f(m3.w));
  }
  for (; e < num; e += 2) {
    int s = csrc[beg + e];
    ushort4 m = T4[(size_t)s * 32 + l32];
    acc.x += h2f(m.x); acc.y += h2f(m.y); acc.z += h2f(m.z); acc.w += h2f(m.w);
  }

  acc.x += __shfl_xor(acc.x, 32);
  acc.y += __shfl_xor(acc.y, 32);
  acc.z += __shfl_xor(acc.z, 32);
  acc.w += __shfl_xor(acc.w, 32);

  if (h == 0) {
    float d = dinv[node];
    float4 bb = ((const float4*)b)[l32];
    float4 o;
    o.x = fmaf(d, acc.x, bb.x);
    o.y = fmaf(d, acc.y, bb.y);
    o.z = fmaf(d, acc.z, bb.z);
    o.w = fmaf(d, acc.w, bb.w);
    if (MODE == 0) {
      ushort4 p;
      p.x = f2h(fmaxf(o.x, 0.f)); p.y = f2h(fmaxf(o.y, 0.f));
      p.z = f2h(fmaxf(o.z, 0.f)); p.w = f2h(fmaxf(o.w, 0.f));
      ((ushort4*)outh)[(size_t)node * 32 + l32] = p;
    } else {
      ((float4*)outf)[(size_t)node * 32 + l32] = o;
    }
  }
}

// ---------------- Pool (2-stage) + final linear ----------------

#define PCHUNK 32

__global__ __launch_bounds__(128) void k_pool1(const float* __restrict__ nemb,
                                               const int* __restrict__ batch,
                                               float* __restrict__ gsum) {
  int g = blockIdx.x >> 5;
  int ck = blockIdx.x & (PCHUNK - 1);
  int c = threadIdx.x;
  int lo = 0, hi = NN;
  while (lo < hi) { int m = (lo + hi) >> 1; if (batch[m] < g) lo = m + 1; else hi = m; }
  int beg = lo;
  hi = NN;
  while (lo < hi) { int m = (lo + hi) >> 1; if (batch[m] < g + 1) lo = m + 1; else hi = m; }
  int end = lo;
  int len = end - beg;
  int c0 = beg + (int)(((long long)len * ck) >> 5);
  int c1 = beg + (int)(((long long)len * (ck + 1)) >> 5);
  float sum = 0.f;
  for (int n = c0; n < c1; ++n) sum += nemb[(size_t)n * CH + c];
  atomicAdd(&gsum[g * CH + c], sum);
}

__global__ __launch_bounds__(128) void k_pool2(const float* __restrict__ gsum,
                                               const int* __restrict__ batch,
                                               const float* __restrict__ Wl,
                                               const float* __restrict__ bl,
                                               float* __restrict__ gout) {
  int g = blockIdx.x;
  int c = threadIdx.x;
  int lo = 0, hi = NN;
  while (lo < hi) { int m = (lo + hi) >> 1; if (batch[m] < g) lo = m + 1; else hi = m; }
  int beg = lo;
  hi = NN;
  while (lo < hi) { int m = (lo + hi) >> 1; if (batch[m] < g + 1) lo = m + 1; else hi = m; }
  int end = lo;
  float gv = gsum[g * CH + c] / fmaxf((float)(end - beg), 1.0f);

  __shared__ float sg[CH];
  sg[c] = gv;
  __syncthreads();
  if (c < OC) {
    float o = bl[c];
    for (int k = 0; k < CH; ++k) o = fmaf(sg[k], Wl[k * OC + c], o);
    gout[g * OC + c] = o;
  }
}

// ---------------- launch ----------------

extern "C" void kernel_launch(void* const* d_in, const int* in_sizes, int n_in,
                              void* d_out, int out_size, void* d_ws, size_t ws_size,
                              hipStream_t stream) {
  const float* x = (const float*)d_in[0];
  const int* ei = (const int*)d_in[1];
  const int* src = ei;
  const int* dst = ei + NE;
  const int* batch = (const int*)d_in[2];
  const float* W1 = (const float*)d_in[3];
  const float* b1 = (const float*)d_in[4];
  const float* W2 = (const float*)d_in[5];
  const float* b2 = (const float*)d_in[6];
  const float* W3 = (const float*)d_in[7];
  const float* b3 = (const float*)d_in[8];
  const float* Wl = (const float*)d_in[9];
  const float* bl = (const float*)d_in[10];

  char* ws = (char*)d_ws;
  size_t off = 0;
  auto alloc = [&](size_t bytes) {
    void* p = ws + off;
    off += (bytes + 255) & ~(size_t)255;
    return p;
  };
  int* cnt = (int*)alloc(NN * 4);
  float* dinv = (float*)alloc(NN * 4);
  int* rp = (int*)alloc(NN * 4);
  int* gcur = (int*)alloc(NB * 4);
  int* bstart = (int*)alloc((NB + 1) * 4);
  int* csrc = (int*)alloc((size_t)NE * 4);
  uint2* pbuf = (uint2*)alloc((size_t)NB * PCAP * 8);     // 12.85 MB
  ushort* thalf = (ushort*)alloc((size_t)NN * CH * 2);    // T' fp16
  ushort* hhalf = (ushort*)alloc((size_t)NN * CH * 2);    // h fp16 (relu'd)
  float* gsum = (float*)alloc((size_t)NG * CH * 4);
  uint4* whf = (uint4*)alloc(3 * 2048 * sizeof(uint4));   // 96 KB fp16 W frags

  float* gout = (float*)d_out;
  float* nemb = (float*)d_out + NG * OC;

  const int nb_g = (NN + 63) / 64;  // 782
  const int nb_a = NN / 4;          // 12500
  const int nb_t = (NE + TILE - 1) / TILE;  // 196 bin tiles

  k_zero<<<33, 256, 0, stream>>>(gcur, gsum);
  k_bin<<<nb_t, 256, 0, stream>>>(src, dst, gcur, pbuf);
  k_prep<<<3, 256, 0, stream>>>(W1, W2, W3, whf);
  k_bscan<<<1, 256, 0, stream>>>(gcur, bstart);
  k_fill2<<<NB, 256, 0, stream>>>(pbuf, gcur, bstart, csrc, cnt, rp, dinv);

  // layer 1: T' = dinv*(x @ W1); h = relu(b1 + dinv*(T'self + sum T'src)) -> fp16
  k_gemm<0><<<nb_g, 256, 0, stream>>>(x, nullptr, whf + 0 * 2048, dinv, thalf);
  k_agg<0><<<nb_a, 256, 0, stream>>>(thalf, rp, cnt, csrc, dinv, b1, hhalf, nullptr);
  // layer 2
  k_gemm<1><<<nb_g, 256, 0, stream>>>(nullptr, hhalf, whf + 1 * 2048, dinv, thalf);
  k_agg<0><<<nb_a, 256, 0, stream>>>(thalf, rp, cnt, csrc, dinv, b2, hhalf, nullptr);
  // layer 3 -> n_emb fp32 straight into d_out (no relu)
  k_gemm<1><<<nb_g, 256, 0, stream>>>(nullptr, hhalf, whf + 2 * 2048, dinv, thalf);
  k_agg<1><<<nb_a, 256, 0, stream>>>(thalf, rp, cnt, csrc, dinv, b3, nullptr, nemb);
  // pool
  k_pool1<<<NG * PCHUNK, 128, 0, stream>>>(nemb, batch, gsum);
  k_pool2<<<NG, 128, 0, stream>>>(gsum, batch, Wl, bl, gout);
}

// Round 7
// 196.388 us; speedup vs baseline: 3.4416x; 1.1079x over previous
//
#include <hip/hip_runtime.h>
#include <hip/hip_fp16.h>

#define NN 50000
#define NE 800000
#define CH 128
#define NG 64
#define OC 10

#define NB 196        // ceil(50000/256) coarse buckets of 256 nodes
#define TILE 4096     // edges per k_bin tile
#define PCAP 8192     // pbuf slots per bucket

typedef _Float16 f16x8 __attribute__((ext_vector_type(8)));
typedef float f32x4 __attribute__((ext_vector_type(4)));

__device__ inline ushort f2h(float x) { __half h = __float2half(x); return __half_as_ushort(h); }
__device__ inline float h2f(ushort u) { return __half2float(__ushort_as_half(u)); }

__device__ inline void h8_unpack(const uint4 u, float* f) {
  f[0] = h2f((ushort)(u.x & 0xffff)); f[1] = h2f((ushort)(u.x >> 16));
  f[2] = h2f((ushort)(u.y & 0xffff)); f[3] = h2f((ushort)(u.y >> 16));
  f[4] = h2f((ushort)(u.z & 0xffff)); f[5] = h2f((ushort)(u.z >> 16));
  f[6] = h2f((ushort)(u.w & 0xffff)); f[7] = h2f((ushort)(u.w >> 16));
}

// ---------------- W fragment prep (+ init duty on block 3) ----------------
// frag f = ks*8 + nt. lane l holds W[ks*32 + 8*(l>>4) + j][nt*16 + (l&15)], j=0..7.

__global__ __launch_bounds__(256) void k_prep(const float* __restrict__ W1, const float* __restrict__ W2,
                                              const float* __restrict__ W3, uint4* __restrict__ whf,
                                              int* __restrict__ gcur, float* __restrict__ gsum) {
  if (blockIdx.x == 3) {  // init duty: zero bucket cursors + pool accumulator
    for (int i = threadIdx.x; i < NB; i += 256) gcur[i] = 0;
    for (int i = threadIdx.x; i < NG * CH; i += 256) gsum[i] = 0.f;
    return;
  }
  const float* W = (blockIdx.x == 0) ? W1 : (blockIdx.x == 1) ? W2 : W3;
  uint4* wh = whf + blockIdx.x * 2048;
  for (int idx = threadIdx.x; idx < 2048; idx += 256) {
    int l = idx & 63, f = idx >> 6;
    int ks = f >> 3, nt = f & 7;
    int k0 = ks * 32 + (l >> 4) * 8;
    int col = nt * 16 + (l & 15);
    ushort h[8];
#pragma unroll
    for (int j = 0; j < 8; ++j) h[j] = f2h(W[(k0 + j) * CH + col]);
    uint4 u;
    u.x = (unsigned)h[0] | ((unsigned)h[1] << 16);
    u.y = (unsigned)h[2] | ((unsigned)h[3] << 16);
    u.z = (unsigned)h[4] | ((unsigned)h[5] << 16);
    u.w = (unsigned)h[6] | ((unsigned)h[7] << 16);
    wh[idx] = u;
  }
}

// ---------------- pass 1: bin edges into 196 coarse buckets, LDS-staged ----------------

__global__ __launch_bounds__(256) void k_bin(const int* __restrict__ src, const int* __restrict__ dst,
                                             int* __restrict__ gcur, uint2* __restrict__ pbuf) {
  __shared__ int scnt[NB];
  __shared__ int soff[NB];
  __shared__ int gbase[NB];
  __shared__ int ssc[256];
  __shared__ uint2 pairs[TILE];
  __shared__ unsigned char bid[TILE];
  const int t = threadIdx.x;

  for (int tile0 = blockIdx.x * TILE; tile0 < NE; tile0 += gridDim.x * TILE) {
    const int tcount = min(TILE, NE - tile0);
    for (int i = t; i < NB; i += 256) scnt[i] = 0;
    __syncthreads();
    for (int i = t; i < tcount; i += 256) {
      int d = dst[tile0 + i];
      atomicAdd(&scnt[d >> 8], 1);
    }
    __syncthreads();
    int v = (t < NB) ? scnt[t] : 0;
    ssc[t] = v;
    __syncthreads();
    for (int d2 = 1; d2 < 256; d2 <<= 1) {
      int x2 = (t >= d2) ? ssc[t - d2] : 0;
      __syncthreads();
      ssc[t] += x2;
      __syncthreads();
    }
    if (t < NB) {
      soff[t] = ssc[t] - v;
      gbase[t] = (v > 0) ? atomicAdd(&gcur[t], v) : 0;
      scnt[t] = ssc[t] - v;
    }
    __syncthreads();
    for (int i = t; i < tcount; i += 256) {
      int s = src[tile0 + i], d = dst[tile0 + i];
      int b = d >> 8;
      int pos = atomicAdd(&scnt[b], 1);
      pairs[pos] = make_uint2((unsigned)s, (unsigned)d);
      bid[pos] = (unsigned char)b;
    }
    __syncthreads();
    for (int i = t; i < tcount; i += 256) {
      int b = bid[i];
      pbuf[((size_t)b << 13) + gbase[b] + (i - soff[b])] = pairs[i];
    }
    __syncthreads();
  }
}

// ---------------- bucket-base scan ----------------

__global__ __launch_bounds__(256) void k_bscan(const int* __restrict__ gcur, int* __restrict__ bstart) {
  int t = threadIdx.x;
  int v = (t < NB) ? gcur[t] : 0;
  __shared__ int s[256];
  s[t] = v;
  __syncthreads();
  for (int d = 1; d < 256; d <<= 1) {
    int x = (t >= d) ? s[t - d] : 0;
    __syncthreads();
    s[t] += x;
    __syncthreads();
  }
  if (t < NB) bstart[t] = s[t] - v;
  if (t == 255) bstart[NB] = s[255];
}

// ---------------- pass 2: per-bucket fill -> csrc, cnt, rp, dinv ----------------

__global__ __launch_bounds__(256) void k_fill2(const uint2* __restrict__ pbuf, const int* __restrict__ gcur,
                                               const int* __restrict__ bstart, int* __restrict__ csrc,
                                               int* __restrict__ cnt, int* __restrict__ rp,
                                               float* __restrict__ dinv) {
  __shared__ int lcnt[256], loff[256], lcur[256], ssc[256];
  const int b = blockIdx.x;
  const int t = threadIdx.x;
  const int n0 = b * 256;
  const int nn = min(256, NN - n0);
  const int beg = bstart[b];
  const int len = gcur[b];
  const uint2* pb = pbuf + ((size_t)b << 13);

  lcnt[t] = 0;
  __syncthreads();
  for (int i = t; i < len; i += 256) {
    atomicAdd(&lcnt[pb[i].y & 255], 1);
  }
  __syncthreads();
  int v = lcnt[t];
  ssc[t] = v;
  __syncthreads();
  for (int d = 1; d < 256; d <<= 1) {
    int x = (t >= d) ? ssc[t - d] : 0;
    __syncthreads();
    ssc[t] += x;
    __syncthreads();
  }
  loff[t] = ssc[t] - v;
  lcur[t] = ssc[t] - v;
  if (t < nn) {
    cnt[n0 + t] = v;
    rp[n0 + t] = beg + loff[t];
    dinv[n0 + t] = rsqrtf((float)(v + 1));  // +1 self loop
  }
  __syncthreads();
  for (int i = t; i < len; i += 256) {
    uint2 p = pb[i];
    int slot = atomicAdd(&lcur[p.y & 255], 1);
    csrc[beg + slot] = (int)p.x;
  }
}

// ---------------- GEMM: T' = dinv * (A @ W) via fp16 MFMA, T stored fp16 ----------------

template <int IN_HALF>
__global__ __launch_bounds__(256) void k_gemm(const float* __restrict__ Af, const ushort* __restrict__ Ah,
                                              const uint4* __restrict__ whf,
                                              const float* __restrict__ dinv, ushort* __restrict__ T) {
  __shared__ ushort sA[64 * 128];  // 16 KB
  const int t = threadIdx.x;
  const int brow = blockIdx.x * 64;

  if (IN_HALF) {
#pragma unroll
    for (int i = 0; i < 4; ++i) {
      int id = t + i * 256;
      int row = id >> 4, c16 = id & 15;
      int gr = brow + row;
      uint4 u = make_uint4(0, 0, 0, 0);
      if (gr < NN) u = ((const uint4*)Ah)[gr * 16 + c16];
      int idx = (row * 128 + c16 * 8) ^ ((row & 7) << 3);
      *(uint4*)&sA[idx] = u;
    }
  } else {
#pragma unroll
    for (int i = 0; i < 8; ++i) {
      int id = t + i * 256;
      int row = id >> 5, c8 = id & 31;
      int gr = brow + row;
      float4 v = make_float4(0.f, 0.f, 0.f, 0.f);
      if (gr < NN) v = ((const float4*)Af)[gr * 32 + c8];
      ushort4 p;
      p.x = f2h(v.x); p.y = f2h(v.y); p.z = f2h(v.z); p.w = f2h(v.w);
      int idx = (row * 128 + c8 * 4) ^ ((row & 7) << 3);
      *(ushort4*)&sA[idx] = p;
    }
  }
  __syncthreads();

  const int w = t >> 6;
  const int l = t & 63;
  const int lr = l & 15;
  const int lk = l >> 4;
  const int arow = w * 16 + lr;

  f16x8 afr[4];
#pragma unroll
  for (int ks = 0; ks < 4; ++ks) {
    int idx = (arow * 128 + ks * 32 + lk * 8) ^ ((arow & 7) << 3);
    afr[ks] = __builtin_bit_cast(f16x8, *(const uint4*)&sA[idx]);
  }

  f32x4 acc[8];
#pragma unroll
  for (int nt = 0; nt < 8; ++nt) acc[nt] = (f32x4)(0.f);

#pragma unroll
  for (int ks = 0; ks < 4; ++ks) {
#pragma unroll
    for (int nt = 0; nt < 8; ++nt) {
      f16x8 bh = __builtin_bit_cast(f16x8, whf[(ks * 8 + nt) * 64 + l]);
      acc[nt] = __builtin_amdgcn_mfma_f32_16x16x32_f16(afr[ks], bh, acc[nt], 0, 0, 0);
    }
  }

#pragma unroll
  for (int i = 0; i < 4; ++i) {
    int grow = brow + w * 16 + lk * 4 + i;
    if (grow < NN) {
      float d = dinv[grow];
#pragma unroll
      for (int nt = 0; nt < 8; ++nt) {
        T[(size_t)grow * CH + nt * 16 + lr] = f2h(acc[nt][i] * d);
      }
    }
  }
}

// ---------------- Aggregation: quarter-wave per node ----------------
// 16 lanes x 16B (ushort8) = full 256B row; 4 nodes/wave, 16 nodes/block.
// No cross-lane reduce; unroll x4 -> 16 gathers in flight per wave.
// MODE 0: out = fp16 relu(...). MODE 1: out = fp32 (n_emb).

template <int MODE>
__global__ __launch_bounds__(256) void k_agg(const ushort* __restrict__ Tp, const int* __restrict__ rp,
                                             const int* __restrict__ cnt, const int* __restrict__ csrc,
                                             const float* __restrict__ dinv, const float* __restrict__ b,
                                             ushort* __restrict__ outh, float* __restrict__ outf) {
  const int node = blockIdx.x * 16 + (threadIdx.x >> 4);  // grid exact: 3125*16
  const int q = threadIdx.x & 15;                          // channels 8q..8q+7
  const uint4* T16 = (const uint4*)Tp;                     // row = 16 uint4

  float a[8];
  {
    uint4 tv = T16[(size_t)node * 16 + q];  // self term
    h8_unpack(tv, a);
  }

  const int beg = rp[node];
  const int num = cnt[node];
  int e = 0;
  for (; e + 3 < num; e += 4) {
    int s0 = csrc[beg + e];
    int s1 = csrc[beg + e + 1];
    int s2 = csrc[beg + e + 2];
    int s3 = csrc[beg + e + 3];
    uint4 m0 = T16[(size_t)s0 * 16 + q];
    uint4 m1 = T16[(size_t)s1 * 16 + q];
    uint4 m2 = T16[(size_t)s2 * 16 + q];
    uint4 m3 = T16[(size_t)s3 * 16 + q];
    float f0[8], f1[8], f2[8], f3[8];
    h8_unpack(m0, f0); h8_unpack(m1, f1); h8_unpack(m2, f2); h8_unpack(m3, f3);
#pragma unroll
    for (int j = 0; j < 8; ++j) a[j] += (f0[j] + f1[j]) + (f2[j] + f3[j]);
  }
  for (; e < num; ++e) {
    int s = csrc[beg + e];
    uint4 m = T16[(size_t)s * 16 + q];
    float f[8];
    h8_unpack(m, f);
#pragma unroll
    for (int j = 0; j < 8; ++j) a[j] += f[j];
  }

  const float d = dinv[node];
  float4 bb0 = ((const float4*)b)[q * 2];
  float4 bb1 = ((const float4*)b)[q * 2 + 1];
  float o[8];
  o[0] = fmaf(d, a[0], bb0.x); o[1] = fmaf(d, a[1], bb0.y);
  o[2] = fmaf(d, a[2], bb0.z); o[3] = fmaf(d, a[3], bb0.w);
  o[4] = fmaf(d, a[4], bb1.x); o[5] = fmaf(d, a[5], bb1.y);
  o[6] = fmaf(d, a[6], bb1.z); o[7] = fmaf(d, a[7], bb1.w);

  if (MODE == 0) {
    uint4 p;
    p.x = (unsigned)f2h(fmaxf(o[0], 0.f)) | ((unsigned)f2h(fmaxf(o[1], 0.f)) << 16);
    p.y = (unsigned)f2h(fmaxf(o[2], 0.f)) | ((unsigned)f2h(fmaxf(o[3], 0.f)) << 16);
    p.z = (unsigned)f2h(fmaxf(o[4], 0.f)) | ((unsigned)f2h(fmaxf(o[5], 0.f)) << 16);
    p.w = (unsigned)f2h(fmaxf(o[6], 0.f)) | ((unsigned)f2h(fmaxf(o[7], 0.f)) << 16);
    ((uint4*)outh)[(size_t)node * 16 + q] = p;
  } else {
    float4* of = (float4*)outf;
    of[(size_t)node * 32 + q * 2] = make_float4(o[0], o[1], o[2], o[3]);
    of[(size_t)node * 32 + q * 2 + 1] = make_float4(o[4], o[5], o[6], o[7]);
  }
}

// ---------------- Pool (2-stage) + final linear ----------------

#define PCHUNK 32

__global__ __launch_bounds__(128) void k_pool1(const float* __restrict__ nemb,
                                               const int* __restrict__ batch,
                                               float* __restrict__ gsum) {
  int g = blockIdx.x >> 5;
  int ck = blockIdx.x & (PCHUNK - 1);
  int c = threadIdx.x;
  int lo = 0, hi = NN;
  while (lo < hi) { int m = (lo + hi) >> 1; if (batch[m] < g) lo = m + 1; else hi = m; }
  int beg = lo;
  hi = NN;
  while (lo < hi) { int m = (lo + hi) >> 1; if (batch[m] < g + 1) lo = m + 1; else hi = m; }
  int end = lo;
  int len = end - beg;
  int c0 = beg + (int)(((long long)len * ck) >> 5);
  int c1 = beg + (int)(((long long)len * (ck + 1)) >> 5);
  float sum = 0.f;
  for (int n = c0; n < c1; ++n) sum += nemb[(size_t)n * CH + c];
  atomicAdd(&gsum[g * CH + c], sum);
}

__global__ __launch_bounds__(128) void k_pool2(const float* __restrict__ gsum,
                                               const int* __restrict__ batch,
                                               const float* __restrict__ Wl,
                                               const float* __restrict__ bl,
                                               float* __restrict__ gout) {
  int g = blockIdx.x;
  int c = threadIdx.x;
  int lo = 0, hi = NN;
  while (lo < hi) { int m = (lo + hi) >> 1; if (batch[m] < g) lo = m + 1; else hi = m; }
  int beg = lo;
  hi = NN;
  while (lo < hi) { int m = (lo + hi) >> 1; if (batch[m] < g + 1) lo = m + 1; else hi = m; }
  int end = lo;
  float gv = gsum[g * CH + c] / fmaxf((float)(end - beg), 1.0f);

  __shared__ float sg[CH];
  sg[c] = gv;
  __syncthreads();
  if (c < OC) {
    float o = bl[c];
    for (int k = 0; k < CH; ++k) o = fmaf(sg[k], Wl[k * OC + c], o);
    gout[g * OC + c] = o;
  }
}

// ---------------- launch ----------------

extern "C" void kernel_launch(void* const* d_in, const int* in_sizes, int n_in,
                              void* d_out, int out_size, void* d_ws, size_t ws_size,
                              hipStream_t stream) {
  const float* x = (const float*)d_in[0];
  const int* ei = (const int*)d_in[1];
  const int* src = ei;
  const int* dst = ei + NE;
  const int* batch = (const int*)d_in[2];
  const float* W1 = (const float*)d_in[3];
  const float* b1 = (const float*)d_in[4];
  const float* W2 = (const float*)d_in[5];
  const float* b2 = (const float*)d_in[6];
  const float* W3 = (const float*)d_in[7];
  const float* b3 = (const float*)d_in[8];
  const float* Wl = (const float*)d_in[9];
  const float* bl = (const float*)d_in[10];

  char* ws = (char*)d_ws;
  size_t off = 0;
  auto alloc = [&](size_t bytes) {
    void* p = ws + off;
    off += (bytes + 255) & ~(size_t)255;
    return p;
  };
  int* cnt = (int*)alloc(NN * 4);
  float* dinv = (float*)alloc(NN * 4);
  int* rp = (int*)alloc(NN * 4);
  int* gcur = (int*)alloc(NB * 4);
  int* bstart = (int*)alloc((NB + 1) * 4);
  int* csrc = (int*)alloc((size_t)NE * 4);
  uint2* pbuf = (uint2*)alloc((size_t)NB * PCAP * 8);     // 12.85 MB
  ushort* thalf = (ushort*)alloc((size_t)NN * CH * 2);    // T' fp16
  ushort* hhalf = (ushort*)alloc((size_t)NN * CH * 2);    // h fp16 (relu'd)
  float* gsum = (float*)alloc((size_t)NG * CH * 4);
  uint4* whf = (uint4*)alloc(3 * 2048 * sizeof(uint4));   // 96 KB fp16 W frags

  float* gout = (float*)d_out;
  float* nemb = (float*)d_out + NG * OC;

  const int nb_g = (NN + 63) / 64;          // 782
  const int nb_a = NN / 16;                 // 3125 (quarter-wave agg)
  const int nb_t = (NE + TILE - 1) / TILE;  // 196 bin tiles

  k_prep<<<4, 256, 0, stream>>>(W1, W2, W3, whf, gcur, gsum);  // + zero duty
  k_bin<<<nb_t, 256, 0, stream>>>(src, dst, gcur, pbuf);
  k_bscan<<<1, 256, 0, stream>>>(gcur, bstart);
  k_fill2<<<NB, 256, 0, stream>>>(pbuf, gcur, bstart, csrc, cnt, rp, dinv);

  // layer 1: T' = dinv*(x @ W1); h = relu(b1 + dinv*(T'self + sum T'src)) -> fp16
  k_gemm<0><<<nb_g, 256, 0, stream>>>(x, nullptr, whf + 0 * 2048, dinv, thalf);
  k_agg<0><<<nb_a, 256, 0, stream>>>(thalf, rp, cnt, csrc, dinv, b1, hhalf, nullptr);
  // layer 2
  k_gemm<1><<<nb_g, 256, 0, stream>>>(nullptr, hhalf, whf + 1 * 2048, dinv, thalf);
  k_agg<0><<<nb_a, 256, 0, stream>>>(thalf, rp, cnt, csrc, dinv, b2, hhalf, nullptr);
  // layer 3 -> n_emb fp32 straight into d_out (no relu)
  k_gemm<1><<<nb_g, 256, 0, stream>>>(nullptr, hhalf, whf + 2 * 2048, dinv, thalf);
  k_agg<1><<<nb_a, 256, 0, stream>>>(thalf, rp, cnt, csrc, dinv, b3, nullptr, nemb);
  // pool
  k_pool1<<<NG * PCHUNK, 128, 0, stream>>>(nemb, batch, gsum);
  k_pool2<<<NG, 128, 0, stream>>>(gsum, batch, Wl, bl, gout);
}